// Round 10
// baseline (417.182 us; speedup 1.0000x reference)
//
#include <hip/hip_runtime.h>
#include <hip/hip_bf16.h>
#include <math.h>

// GlobalSceneTokenizer fused pipeline, f32 in/out.
// R24 = R23 (reproduced optimum: k_main 286us, total 390) + LN1 mean
// factoring. s1_LN1[r] = SU[j] + SV'[c] + rel[r].w1bs (linear in input ->
// exact modulo f32 association): SU/SV' precomputed per point in k_pre
// (in-register rowsums, ~50 VALU/wave), w1bs in k_prep. Removes the P3
// cooperative s1 (192 VALU/thread on ALL threads) -> ~75-inst dot on
// tid<128. s2 (nonlinear) stays cooperative; LN2 untouched (factored form
// nets ~0). reds s1-traffic in P3 eliminated.
// Everything else byte-identical to R23/R20: R18 factored stage-1
// (U[j]=pf@w1a, V'[c]=absemb@w1c+b1 in k_pre), k_main stage-1 = C-init
// gather(U)+V' + one K=32 rel MFMA, stage-2 K=256 pi-permuted, 128 rows
// 8 waves 2Mx4N, R19/R20 atomic-floor removal (32-replica pooled, LDS
// pre-reduce, separate k_final).
// Canary: VGPR_Count must stay 64 (128 unified regs = exactly the 16-wave/CU
// ceiling; any increase halves occupancy).

#define LN_EPS 1e-5f

typedef __attribute__((ext_vector_type(8))) short bf16x8;
typedef __attribute__((ext_vector_type(4))) float f32x4;
typedef __attribute__((ext_vector_type(2))) unsigned int u32x2;
typedef __attribute__((ext_vector_type(4))) unsigned int u32x4;

#if __has_builtin(__builtin_amdgcn_rcpf)
#define FRCP(x) __builtin_amdgcn_rcpf(x)
#else
#define FRCP(x) (1.0f / (x))
#endif

__device__ __forceinline__ unsigned short f2bf(float f) {
    unsigned int x = __float_as_uint(f);
    return (unsigned short)((x + 0x7FFFu + ((x >> 16) & 1u)) >> 16);  // RNE
}
__device__ __forceinline__ float bf2f(unsigned short s) {
    return __uint_as_float(((unsigned int)s) << 16);
}
__device__ __forceinline__ unsigned int pack2(float a, float b) {
    union { __hip_bfloat162 h; unsigned int u; } cvt;
    cvt.h = __float22bfloat162_rn(make_float2(a, b));
    return cvt.u;
}
__device__ __forceinline__ unsigned int fenc(float f) {
    unsigned int u = __float_as_uint(f);
    return (u & 0x80000000u) ? ~u : (u | 0x80000000u);
}
__device__ __forceinline__ float fdec(unsigned int u) {
    return __uint_as_float((u & 0x80000000u) ? (u & 0x7FFFFFFFu) : ~u);
}
__device__ __forceinline__ float gelu_fast(float x) {
    float x2 = x * x;
    float u = x * fmaf(0.0356774081f, x2, 0.7978845608f);
    float e = exp2f(u * -2.8853900818f);   // e^{-2u}
    float r = FRCP(e + 1.0f);              // sigma(2u)
    return x * r;
}
template<int CTRL>
__device__ __forceinline__ float dppadd(float s) {
    int v = __builtin_amdgcn_update_dpp(0, __float_as_int(s), CTRL, 0xF, 0xF, true);
    return s + __int_as_float(v);
}
__device__ __forceinline__ float rowsum16(float x) {
    x = dppadd<0x128>(x);   // ror:8
    x = dppadd<0x124>(x);   // ror:4
    x = dppadd<0x122>(x);   // ror:2
    x = dppadd<0x121>(x);   // ror:1
    return x;
}

// ---------------- K_prep ----------------------------------------------------
// blk 0..15 : w2T [n=256][k=256], k pi-permuted: pi(nt*16+lo)=lo*4+nt per 64-blk
// blk 16..19: w1aT [n=256][k=64]   (w1 rows 0..63, pf part)
// blk 20..27: w1cT [n=256][k=96]   (w1 rows 91..186, abs part)
// blk 28    : w1bT [n=256][k=32]   (w1 rows 64..90 rel part, pad 0)
// blk 29    : pooled_r init (32 replicas x 1024)
// blk 30    : w1bs[32] = sum_n bf16(w1b[k][n])  (f32; k>=27 -> 0)
__global__ __launch_bounds__(256) void k_prep(
    const float* __restrict__ w1, const float* __restrict__ w2,
    unsigned short* __restrict__ w2T, unsigned short* __restrict__ w1aT,
    unsigned short* __restrict__ w1cT, unsigned short* __restrict__ w1bT,
    unsigned int* __restrict__ pooled_r, float* __restrict__ w1bs)
{
    int t = threadIdx.x, blk = blockIdx.x;
    if (blk < 16) {                      // w2T: [n=256][k=256 permuted]
        __shared__ unsigned short tile[64][65];
        int tr = blk >> 2, tc = blk & 3;
        #pragma unroll
        for (int rr = 0; rr < 16; ++rr) {
            int kl = rr * 4 + (t >> 6), nl = t & 63;
            tile[kl][nl] = f2bf(w2[(size_t)(tr * 64 + kl) * 256 + tc * 64 + nl]);
        }
        __syncthreads();
        #pragma unroll
        for (int rr = 0; rr < 16; ++rr) {
            int nl = rr * 4 + (t >> 6), kp = t & 63;
            int kl = (kp & 3) * 16 + (kp >> 2);      // pi^-1
            w2T[(size_t)(tc * 64 + nl) * 256 + tr * 64 + kp] = tile[kl][nl];
        }
    } else if (blk < 20) {               // w1aT: [256][64]
        __shared__ unsigned short tile[64][65];
        int tc = blk - 16;
        #pragma unroll
        for (int rr = 0; rr < 16; ++rr) {
            int kl = rr * 4 + (t >> 6), nl = t & 63;
            tile[kl][nl] = f2bf(w1[(size_t)kl * 256 + tc * 64 + nl]);
        }
        __syncthreads();
        #pragma unroll
        for (int rr = 0; rr < 16; ++rr) {
            int nl = rr * 4 + (t >> 6), kl = t & 63;
            w1aT[(size_t)(tc * 64 + nl) * 64 + kl] = tile[kl][nl];
        }
    } else if (blk < 28) {               // w1cT: [256][96] from w1 rows 91..186
        __shared__ unsigned short tile[64][65];
        int idx = blk - 20;
        int tr2 = idx >> 2, tc = idx & 3;
        #pragma unroll
        for (int rr = 0; rr < 16; ++rr) {
            int kl = rr * 4 + (t >> 6), nl = t & 63;
            int k = tr2 * 64 + kl;
            float v = 0.f;
            if (k < 96) v = w1[(size_t)(91 + k) * 256 + tc * 64 + nl];
            tile[kl][nl] = f2bf(v);
        }
        __syncthreads();
        #pragma unroll
        for (int rr = 0; rr < 16; ++rr) {
            int nl = rr * 4 + (t >> 6), kl = t & 63;
            int k = tr2 * 64 + kl;
            if (k < 96)
                w1cT[(size_t)(tc * 64 + nl) * 96 + k] = tile[kl][nl];
        }
    } else if (blk == 28) {              // w1bT: [256][32], rel part
        int n = t;
        #pragma unroll
        for (int k = 0; k < 32; ++k) {
            unsigned short v = 0;
            if (k < 27) v = f2bf(w1[(size_t)(64 + k) * 256 + n]);
            w1bT[(size_t)n * 32 + k] = v;
        }
    } else if (blk == 29) {
        unsigned int idv = fenc(-1e19f);
        for (int q = t; q < 32768; q += 256) pooled_r[q] = idv;
    } else {                             // w1bs: col sums of bf16 rel weights
        if (t < 32) {
            float s = 0.f;
            if (t < 27) {
                const float* row = w1 + (size_t)(64 + t) * 256;
                for (int n = 0; n < 256; ++n) s += bf2f(f2bf(row[n]));
            }
            w1bs[t] = s;
        }
    }
}

// ---------------- K_pre: U[p]=pf@w1a, V'[p]=absemb@w1c+b1 (pi-permuted f32) --
// + SU[p]=sum_n U[p][n], SV[p]=sum_n V'[p][n]  (for factored LN1 mean)
// 1024 blocks x 256 threads; 16 rows/block; wave = 16 rows x 64 cols (wvN=wv)
__global__ __launch_bounds__(256) void k_pre(
    const float* __restrict__ xyz, const float* __restrict__ pf,
    const unsigned short* __restrict__ w1aT, const unsigned short* __restrict__ w1cT,
    const float* __restrict__ b1,
    float* __restrict__ U_p, float* __restrict__ V_p,
    float* __restrict__ SU_p, float* __restrict__ SV_p)
{
    __shared__ __align__(16) unsigned short ptile[16 * 72];    // pf bf16
    __shared__ __align__(16) unsigned short etile[16 * 104];   // abs emb bf16
    __shared__ float sred[16][4][2];                           // row sums U/V
    int tid = threadIdx.x, wv = tid >> 6, lane = tid & 63;
    int lo16 = lane & 15, quad = lane >> 4;
    int rows0 = blockIdx.x * 16;

    // stage pf (16 rows x 64 cols): thread = (row, 4-float seg)
    {
        int r = tid >> 4, seg = tid & 15;
        f32x4 v = *(const f32x4*)(pf + (size_t)(rows0 + r) * 64 + seg * 4);
        u32x2 o; o.x = pack2(v.x, v.y); o.y = pack2(v.z, v.w);
        *(u32x2*)&ptile[r * 72 + seg * 4] = o;
    }
    // stage abs sin-emb (16 rows x 48 pairs = 768 items); 3 items/thread
    #pragma unroll
    for (int q = 0; q < 3; ++q) {
        int item = q * 256 + tid;
        int r = item / 48, pr = item - 48 * r;
        float vals[2];
        #pragma unroll
        for (int qq = 0; qq < 2; ++qq) {
            int cc = pr * 2 + qq;
            int a = cc >> 5, wI = cc & 31;
            int jf = (wI < 16) ? wI : (wI - 16);
            float coord = xyz[(size_t)(rows0 + r) * 3 + a];
            float fr = __expf(-0.61402269146507894f * (float)jf);
            float ang = coord * fr;
            vals[qq] = (wI < 16) ? __sinf(ang) : __cosf(ang);
        }
        *(unsigned int*)&etile[r * 104 + 2 * pr] = pack2(vals[0], vals[1]);
    }
    __syncthreads();

    // U GEMM: K=64, C-init 0; wave covers cols wv*64..+64 of its 16 rows
    f32x4 acc[4];
    #pragma unroll
    for (int nt = 0; nt < 4; ++nt) acc[nt] = (f32x4){0.f, 0.f, 0.f, 0.f};
    #pragma unroll
    for (int ks = 0; ks < 2; ++ks) {
        bf16x8 afr = *(const bf16x8*)&ptile[lo16 * 72 + ks * 32 + quad * 8];
        #pragma unroll
        for (int nt = 0; nt < 4; ++nt) {
            int n = wv * 64 + nt * 16 + lo16;
            bf16x8 bfr = *(const bf16x8*)&w1aT[(size_t)n * 64 + ks * 32 + quad * 8];
            acc[nt] = __builtin_amdgcn_mfma_f32_16x16x32_bf16(afr, bfr, acc[nt], 0, 0, 0);
        }
    }
    #pragma unroll
    for (int reg = 0; reg < 4; ++reg) {
        f32x4 o = {acc[0][reg], acc[1][reg], acc[2][reg], acc[3][reg]};
        *(f32x4*)&U_p[(size_t)(rows0 + quad * 4 + reg) * 256 + wv * 64 + lo16 * 4] = o;
    }
    // SU partial: sum of this wave's 64 cols per row
    #pragma unroll
    for (int reg = 0; reg < 4; ++reg) {
        float s = acc[0][reg] + acc[1][reg] + acc[2][reg] + acc[3][reg];
        s = rowsum16(s);
        if (lo16 == 0) sred[quad * 4 + reg][wv][0] = s;
    }

    // V GEMM: K=96, C-init = b1 (folded)
    {
        float b1f[4];
        #pragma unroll
        for (int nt = 0; nt < 4; ++nt) b1f[nt] = b1[wv * 64 + nt * 16 + lo16];
        #pragma unroll
        for (int nt = 0; nt < 4; ++nt)
            #pragma unroll
            for (int reg = 0; reg < 4; ++reg) acc[nt][reg] = b1f[nt];
    }
    #pragma unroll
    for (int ks = 0; ks < 3; ++ks) {
        bf16x8 afr = *(const bf16x8*)&etile[lo16 * 104 + ks * 32 + quad * 8];
        #pragma unroll
        for (int nt = 0; nt < 4; ++nt) {
            int n = wv * 64 + nt * 16 + lo16;
            bf16x8 bfr = *(const bf16x8*)&w1cT[(size_t)n * 96 + ks * 32 + quad * 8];
            acc[nt] = __builtin_amdgcn_mfma_f32_16x16x32_bf16(afr, bfr, acc[nt], 0, 0, 0);
        }
    }
    #pragma unroll
    for (int reg = 0; reg < 4; ++reg) {
        f32x4 o = {acc[0][reg], acc[1][reg], acc[2][reg], acc[3][reg]};
        *(f32x4*)&V_p[(size_t)(rows0 + quad * 4 + reg) * 256 + wv * 64 + lo16 * 4] = o;
    }
    // SV partial
    #pragma unroll
    for (int reg = 0; reg < 4; ++reg) {
        float s = acc[0][reg] + acc[1][reg] + acc[2][reg] + acc[3][reg];
        s = rowsum16(s);
        if (lo16 == 0) sred[quad * 4 + reg][wv][1] = s;
    }
    __syncthreads();
    if (tid < 16) {
        float su = sred[tid][0][0] + sred[tid][1][0] + sred[tid][2][0] + sred[tid][3][0];
        float sv = sred[tid][0][1] + sred[tid][1][1] + sred[tid][2][1] + sred[tid][3][1];
        SU_p[rows0 + tid] = su;
        SV_p[rows0 + tid] = sv;
    }
}

// ---------------- K_main ---------------------------------------------------
__global__ __launch_bounds__(512, 4) void k_main(
    const float* __restrict__ xyz,
    const unsigned short* __restrict__ w1bT, const unsigned short* __restrict__ w2T,
    const float* __restrict__ U_p, const float* __restrict__ V_p,
    const float* __restrict__ SU_p, const float* __restrict__ SV_p,
    const float* __restrict__ w1bs,
    const float* __restrict__ g1, const float* __restrict__ be1,
    const float* __restrict__ b2, const float* __restrict__ g2,
    const float* __restrict__ be2,
    unsigned int* __restrict__ pooled_r)
{
    // rels (128 x 32+8, stride 40) unioned with h1s (128 x 256+8, stride 264)
    __shared__ __align__(16) unsigned short smem[128 * 264];   // 67584 B
    __shared__ unsigned long long bmask[4][64];
    __shared__ int   idxs[128];
    __shared__ float ctr[4][3];
    __shared__ float reds[128][4][2];
    __shared__ float musig[128][2];
    __shared__ unsigned int pool_s[256];
    unsigned short* rels = smem;  // stride 40 (dead once stage-1 MFMAs done)
    unsigned short* h1s  = smem;  // stride 264 (k-permuted within 64-blocks)

    const int N = 4096;
    int tid = threadIdx.x, wv = tid >> 6, lane = tid & 63;
    int lo16 = lane & 15, quad = lane >> 4;
    int wvM = wv >> 2, wvN = wv & 3;           // 2(M) x 4(N) wave grid
    int b = blockIdx.x & 3;                    // batch-major for L2 locality
    int i0 = (blockIdx.x >> 2) * 4;
    int rep = (blockIdx.x >> 2) & 31;          // pooled replica
    size_t base = (size_t)b * N;
    const float* xb = xyz + base * 3;

    // hoisted: rel-part stage-1 weights (independent of LDS)
    bf16x8 bfrR[4];
    #pragma unroll
    for (int nt = 0; nt < 4; ++nt) {
        int n = wvN * 64 + nt * 16 + lo16;
        bfrR[nt] = *(const bf16x8*)&w1bT[(size_t)n * 32 + quad * 8];
    }

    // P0a: centers + pool_s init
    if (tid < 256) pool_s[tid] = fenc(-1e19f);
    if (tid < 12) { int p = tid / 3, a = tid - 3 * p; ctr[p][a] = xb[(i0 + p) * 3 + a]; }
    // exact fp32 threshold: largest float <= (double)0.16*0.16  (validated R9)
    const double r2d = 0.16 * 0.16;
    float T = (float)r2d;
    if ((double)T > r2d) T = __uint_as_float(__float_as_uint(T) - 1u);
    // P0c phase A: each wave scans 8 chunks, all 4 centers per point load
    {
        f32x4 cA = *(const f32x4*)(xb + (size_t)i0 * 3);
        f32x4 cB = *(const f32x4*)(xb + (size_t)i0 * 3 + 4);
        f32x4 cC = *(const f32x4*)(xb + (size_t)i0 * 3 + 8);
        float cx0 = cA.x, cy0 = cA.y, cz0 = cA.z;
        float cx1 = cA.w, cy1 = cB.x, cz1 = cB.y;
        float cx2 = cB.z, cy2 = cB.w, cz2 = cC.x;
        float cx3 = cC.y, cy3 = cC.z, cz3 = cC.w;
        #pragma unroll 2
        for (int i = 0; i < 8; ++i) {
            int chunk = wv * 8 + i;
            int j = chunk * 64 + lane;
            const float* pp = xb + (size_t)j * 3;
            float px = pp[0], py = pp[1], pz = pp[2];
            float dx0 = __fsub_rn(px, cx0), dy0 = __fsub_rn(py, cy0), dz0 = __fsub_rn(pz, cz0);
            float sq0 = __fadd_rn(__fadd_rn(__fmul_rn(dx0, dx0), __fmul_rn(dy0, dy0)),
                                  __fmul_rn(dz0, dz0));
            unsigned long long m0 = __ballot(sq0 <= T);
            float dx1 = __fsub_rn(px, cx1), dy1 = __fsub_rn(py, cy1), dz1 = __fsub_rn(pz, cz1);
            float sq1 = __fadd_rn(__fadd_rn(__fmul_rn(dx1, dx1), __fmul_rn(dy1, dy1)),
                                  __fmul_rn(dz1, dz1));
            unsigned long long m1 = __ballot(sq1 <= T);
            float dx2 = __fsub_rn(px, cx2), dy2 = __fsub_rn(py, cy2), dz2 = __fsub_rn(pz, cz2);
            float sq2 = __fadd_rn(__fadd_rn(__fmul_rn(dx2, dx2), __fmul_rn(dy2, dy2)),
                                  __fmul_rn(dz2, dz2));
            unsigned long long m2 = __ballot(sq2 <= T);
            float dx3 = __fsub_rn(px, cx3), dy3 = __fsub_rn(py, cy3), dz3 = __fsub_rn(pz, cz3);
            float sq3 = __fadd_rn(__fadd_rn(__fmul_rn(dx3, dx3), __fmul_rn(dy3, dy3)),
                                  __fmul_rn(dz3, dz3));
            unsigned long long m3 = __ballot(sq3 <= T);
            if (lane == 0) {
                bmask[0][chunk] = m0; bmask[1][chunk] = m1;
                bmask[2][chunk] = m2; bmask[3][chunk] = m3;
            }
        }
    }
    __syncthreads();
    // P0c phase B: waves 0..3 select first 32 by ascending index (one center each)
    if (wv < 4) {
        int p = wv;
        unsigned long long m = bmask[p][lane];
        int c = __popcll(m);
        int inc = c;
        #pragma unroll
        for (int d = 1; d <= 32; d <<= 1) {
            int v = __shfl_up(inc, d);
            if (lane >= d) inc += v;
        }
        int exc = inc - c;
        int total = __shfl(inc, 63);
        unsigned long long lm = __ballot(m != 0ull);
        int fl = __ffsll(lm) - 1;                       // total>=1 (center in ball)
        unsigned long long mf = (unsigned long long)__shfl((long long)m, fl);
        int firstj = fl * 64 + __ffsll(mf) - 1;
        unsigned long long mm = m;
        int t = 0;
        while (mm != 0ull && (exc + t) < 32) {
            int bpos = __ffsll(mm) - 1;
            idxs[p * 32 + exc + t] = lane * 64 + bpos;
            mm &= mm - 1; ++t;
        }
        if (lane >= total && lane < 32) idxs[p * 32 + lane] = firstj;  // pad
    }
    __syncthreads();

    // P1b: rel xyz (cols 0..2) + rel emb (3..26) + zeros (27..31)
    {
        int r = tid & 127, part = tid >> 7;
        int p = r >> 5;
        int j = idxs[r];
        float rx = xb[j * 3]     - ctr[p][0];
        float ry = xb[j * 3 + 1] - ctr[p][1];
        float rz = xb[j * 3 + 2] - ctr[p][2];
        unsigned short* arow = &rels[r * 40];
        if (part == 0) {
            *(unsigned int*)&arow[0] = pack2(rx, ry);
            arow[2] = f2bf(rz);
            arow[27] = 0;
            *(u32x2*)&arow[28] = (u32x2){0u, 0u};
        } else {
            int a = part - 1;
            float cv = (a == 0) ? rx : ((a == 1) ? ry : rz);
            const float fr4[4] = {1.f, 0.046415888336127774f,
                                  0.0021544346900318843f, 1e-4f};  // 10000^(-j/3)
            float sn[4], cs[4];
            #pragma unroll
            for (int tt = 0; tt < 4; ++tt) {
                float ang = cv * fr4[tt];
                sn[tt] = __sinf(ang); cs[tt] = __cosf(ang);
            }
            arow[3 + a * 8 + 0] = f2bf(sn[0]); arow[3 + a * 8 + 1] = f2bf(sn[1]);
            arow[3 + a * 8 + 2] = f2bf(sn[2]); arow[3 + a * 8 + 3] = f2bf(sn[3]);
            arow[3 + a * 8 + 4] = f2bf(cs[0]); arow[3 + a * 8 + 5] = f2bf(cs[1]);
            arow[3 + a * 8 + 6] = f2bf(cs[2]); arow[3 + a * 8 + 7] = f2bf(cs[3]);
        }
    }
    __syncthreads();

    // P2: C-init = U[j] + V'[c]  (b1 folded into V'); then rel MFMA K=32
    const int arow0 = wvM * 64;
    f32x4 acc[4][4];
    #pragma unroll
    for (int mt = 0; mt < 4; ++mt) {
        int cl = wvM * 2 + (mt >> 1);   // center of rows [arow0+mt*16, +16)
        f32x4 vv = *(const f32x4*)&V_p[(size_t)(base + i0 + cl) * 256 + wvN * 64 + lo16 * 4];
        #pragma unroll
        for (int reg = 0; reg < 4; ++reg) {
            int r = arow0 + mt * 16 + quad * 4 + reg;
            int j = idxs[r];
            f32x4 uu = *(const f32x4*)&U_p[(size_t)(base + j) * 256 + wvN * 64 + lo16 * 4];
            #pragma unroll
            for (int nt = 0; nt < 4; ++nt) acc[mt][nt][reg] = uu[nt] + vv[nt];
        }
    }
    #pragma unroll
    for (int mt = 0; mt < 4; ++mt) {
        bf16x8 afr = *(const bf16x8*)&rels[(arow0 + mt * 16 + lo16) * 40 + quad * 8];
        #pragma unroll
        for (int nt = 0; nt < 4; ++nt)
            acc[mt][nt] = __builtin_amdgcn_mfma_f32_16x16x32_bf16(
                afr, bfrR[nt], acc[mt][nt], 0, 0, 0);
    }

    // P3: LN1 stats: s2 cooperative (DPP + reds), s1 FACTORED (SU+SV+dot32)
    #pragma unroll
    for (int mt = 0; mt < 4; ++mt) {
        #pragma unroll
        for (int reg = 0; reg < 4; ++reg) {
            float s2 = 0.f;
            #pragma unroll
            for (int nt = 0; nt < 4; ++nt) { float v = acc[mt][nt][reg]; s2 = fmaf(v, v, s2); }
            s2 = rowsum16(s2);
            if (lo16 == 0) {
                int r = arow0 + mt * 16 + quad * 4 + reg;
                reds[r][wvN][0] = s2;
            }
        }
    }
    __syncthreads();   // reds ready; all waves done reading rels (dot below
                       // runs before the next barrier; h1s writes come after)
    if (tid < 128) {
        int r = tid;
        float s2 = reds[r][0][0] + reds[r][1][0] + reds[r][2][0] + reds[r][3][0];
        int j = idxs[r];
        float s1 = SU_p[base + j] + SV_p[base + i0 + (r >> 5)];
        const bf16x8* rrow = (const bf16x8*)&rels[r * 40];
        #pragma unroll
        for (int f = 0; f < 4; ++f) {
            bf16x8 fr = rrow[f];
            #pragma unroll
            for (int e = 0; e < 8; ++e)
                s1 = fmaf(bf2f((unsigned short)fr[e]), w1bs[f * 8 + e], s1);
        }
        float mu = s1 * (1.f / 256.f);
        float var = fmaxf(s2 * (1.f / 256.f) - mu * mu, 0.f);
        musig[r][0] = mu; musig[r][1] = rsqrtf(var + LN_EPS);
    }
    __syncthreads();
    {
        float g1f[4], be1f[4];
        #pragma unroll
        for (int nt = 0; nt < 4; ++nt) {
            int n = wvN * 64 + nt * 16 + lo16;
            g1f[nt] = g1[n]; be1f[nt] = be1[n];
        }
        #pragma unroll
        for (int mt = 0; mt < 4; ++mt) {
            #pragma unroll
            for (int reg = 0; reg < 4; ++reg) {
                int r = arow0 + mt * 16 + quad * 4 + reg;
                float mu = musig[r][0], rs = musig[r][1];
                float v0 = gelu_fast(fmaf((acc[mt][0][reg] - mu) * rs, g1f[0], be1f[0]));
                float v1 = gelu_fast(fmaf((acc[mt][1][reg] - mu) * rs, g1f[1], be1f[1]));
                float v2 = gelu_fast(fmaf((acc[mt][2][reg] - mu) * rs, g1f[2], be1f[2]));
                float v3 = gelu_fast(fmaf((acc[mt][3][reg] - mu) * rs, g1f[3], be1f[3]));
                u32x2 w; w.x = pack2(v0, v1); w.y = pack2(v2, v3);
                *(u32x2*)&h1s[r * 264 + wvN * 64 + lo16 * 4] = w;   // pi(n)=lo16*4+nt
            }
        }
    }
    __syncthreads();   // h1s ready

    // P4: stage-2 MFMA K=256 (pi-permuted; w2T matches); C-init = b2
    {
        float b2f[4];
        #pragma unroll
        for (int nt = 0; nt < 4; ++nt) b2f[nt] = b2[wvN * 64 + nt * 16 + lo16];
        #pragma unroll
        for (int mt = 0; mt < 4; ++mt)
            #pragma unroll
            for (int nt = 0; nt < 4; ++nt)
                #pragma unroll
                for (int reg = 0; reg < 4; ++reg) acc[mt][nt][reg] = b2f[nt];
    }
    for (int ks = 0; ks < 8; ++ks) {
        bf16x8 bfr[4], afr[4];
        #pragma unroll
        for (int nt = 0; nt < 4; ++nt) {
            int n = wvN * 64 + nt * 16 + lo16;
            bfr[nt] = *(const bf16x8*)&w2T[(size_t)n * 256 + ks * 32 + quad * 8];
        }
        #pragma unroll
        for (int mt = 0; mt < 4; ++mt)
            afr[mt] = *(const bf16x8*)&h1s[(arow0 + mt * 16 + lo16) * 264 + ks * 32 + quad * 8];
        #pragma unroll
        for (int mt = 0; mt < 4; ++mt)
            #pragma unroll
            for (int nt = 0; nt < 4; ++nt)
                acc[mt][nt] = __builtin_amdgcn_mfma_f32_16x16x32_bf16(
                    afr[mt], bfr[nt], acc[mt][nt], 0, 0, 0);
    }

    // P5: LN2 stats (DPP + reds, unchanged), normalize, col-max -> pool_s
    {
        #pragma unroll
        for (int mt = 0; mt < 4; ++mt) {
            #pragma unroll
            for (int reg = 0; reg < 4; ++reg) {
                float s1 = 0.f, s2 = 0.f;
                #pragma unroll
                for (int nt = 0; nt < 4; ++nt) { float v = acc[mt][nt][reg]; s1 += v; s2 = fmaf(v, v, s2); }
                s1 = rowsum16(s1); s2 = rowsum16(s2);
                if (lo16 == 0) {
                    int r = arow0 + mt * 16 + quad * 4 + reg;
                    reds[r][wvN][0] = s1; reds[r][wvN][1] = s2;
                }
            }
        }
        __syncthreads();
        if (tid < 128) {
            int r = tid;
            float s1 = reds[r][0][0] + reds[r][1][0] + reds[r][2][0] + reds[r][3][0];
            float s2 = reds[r][0][1] + reds[r][1][1] + reds[r][2][1] + reds[r][3][1];
            float mu = s1 * (1.f / 256.f);
            float var = fmaxf(s2 * (1.f / 256.f) - mu * mu, 0.f);
            musig[r][0] = mu; musig[r][1] = rsqrtf(var + LN_EPS);
        }
        __syncthreads();

        float g2f[4], be2f[4];
        #pragma unroll
        for (int nt = 0; nt < 4; ++nt) {
            int n = wvN * 64 + nt * 16 + lo16;
            g2f[nt] = g2[n]; be2f[nt] = be2[n];
        }
        float mx[4] = {-1e30f, -1e30f, -1e30f, -1e30f};
        #pragma unroll
        for (int mt = 0; mt < 4; ++mt) {
            #pragma unroll
            for (int reg = 0; reg < 4; ++reg) {
                int r = arow0 + mt * 16 + quad * 4 + reg;
                float mu = musig[r][0], rs = musig[r][1];
                #pragma unroll
                for (int nt = 0; nt < 4; ++nt) {
                    float v = fmaf((acc[mt][nt][reg] - mu) * rs, g2f[nt], be2f[nt]);
                    mx[nt] = fmaxf(mx[nt], v);
                }
            }
        }
        #pragma unroll
        for (int nt = 0; nt < 4; ++nt) {
            mx[nt] = fmaxf(mx[nt], __shfl_xor(mx[nt], 16));
            mx[nt] = fmaxf(mx[nt], __shfl_xor(mx[nt], 32));
        }
        if (quad == 0) {
            #pragma unroll
            for (int nt = 0; nt < 4; ++nt)
                atomicMax(&pool_s[wvN * 64 + nt * 16 + lo16], fenc(mx[nt]));
        }
    }
    // flush pool_s to this block's replica (256 coalesced atomics)
    __syncthreads();
    if (tid < 256)
        atomicMax(pooled_r + rep * 1024 + b * 256 + tid, pool_s[tid]);
}

// ---------------- K_final: replica max-reduce + final MLPs ------------------
// 4 blocks (one per batch) x 256 threads; thread owns output col c = tid.
__global__ __launch_bounds__(256) void k_final(
    const unsigned int* __restrict__ pooled_r,
    const float* __restrict__ pw1, const float* __restrict__ pb1,
    const float* __restrict__ pg1, const float* __restrict__ pbe1,
    const float* __restrict__ pw2, const float* __restrict__ pb2,
    const float* __restrict__ pg2, const float* __restrict__ pbe2,
    float* __restrict__ out)
{
    __shared__ float xw[256], xh[256];
    __shared__ float lred[2][4];
    int tid = threadIdx.x, wv = tid >> 6;
    int bb = blockIdx.x;

    // replica max-reduce for this thread's column
    {
        unsigned int mv = pooled_r[bb * 256 + tid];
        #pragma unroll
        for (int r = 1; r < 32; ++r) {
            unsigned int v = pooled_r[r * 1024 + bb * 256 + tid];
            mv = (v > mv) ? v : mv;
        }
        xw[tid] = fdec(mv);
    }
    __syncthreads();

    // MLP1: a1[c] = pb1[c] + sum_k xw[k]*pw1[k][c]
    float a1 = pb1[tid];
    #pragma unroll 8
    for (int k = 0; k < 256; ++k)
        a1 = fmaf(xw[k], pw1[(size_t)k * 256 + tid], a1);
    // LN over cols (4-wave reduce)
    float s1 = a1, s2 = a1 * a1;
    s1 = rowsum16(s1); s2 = rowsum16(s2);
    s1 += __shfl_xor(s1, 16); s2 += __shfl_xor(s2, 16);
    s1 += __shfl_xor(s1, 32); s2 += __shfl_xor(s2, 32);
    if ((tid & 63) == 0) { lred[0][wv] = s1; lred[1][wv] = s2; }
    __syncthreads();
    s1 = lred[0][0] + lred[0][1] + lred[0][2] + lred[0][3];
    s2 = lred[1][0] + lred[1][1] + lred[1][2] + lred[1][3];
    float mu = s1 * (1.f / 256.f);
    float rs = rsqrtf(fmaxf(s2 * (1.f / 256.f) - mu * mu, 0.f) + LN_EPS);
    xh[tid] = gelu_fast(fmaf((a1 - mu) * rs, pg1[tid], pbe1[tid]));
    __syncthreads();

    // MLP2
    float a2 = pb2[tid];
    #pragma unroll 8
    for (int k = 0; k < 256; ++k)
        a2 = fmaf(xh[k], pw2[(size_t)k * 256 + tid], a2);
    s1 = a2; s2 = a2 * a2;
    s1 = rowsum16(s1); s2 = rowsum16(s2);
    s1 += __shfl_xor(s1, 16); s2 += __shfl_xor(s2, 16);
    s1 += __shfl_xor(s1, 32); s2 += __shfl_xor(s2, 32);
    if ((tid & 63) == 0) { lred[0][wv] = s1; lred[1][wv] = s2; }
    __syncthreads();
    s1 = lred[0][0] + lred[0][1] + lred[0][2] + lred[0][3];
    s2 = lred[1][0] + lred[1][1] + lred[1][2] + lred[1][3];
    mu = s1 * (1.f / 256.f);
    rs = rsqrtf(fmaxf(s2 * (1.f / 256.f) - mu * mu, 0.f) + LN_EPS);
    out[bb * 256 + tid] = fmaf((a2 - mu) * rs, pg2[tid], pbe2[tid]);
}

// ---------------- launch ---------------------------------------------------
extern "C" void kernel_launch(void* const* d_in, const int* in_sizes, int n_in,
                              void* d_out, int out_size, void* d_ws, size_t ws_size,
                              hipStream_t stream)
{
    char* ws = (char*)d_ws;
    unsigned short* w2T      = (unsigned short*)ws;                      // 128 KB
    unsigned short* w1aT     = (unsigned short*)(ws + (128u << 10));     // 32 KB
    unsigned short* w1cT     = (unsigned short*)(ws + (160u << 10));     // 48 KB
    unsigned short* w1bT     = (unsigned short*)(ws + (208u << 10));     // 16 KB
    unsigned int*   pooled_r = (unsigned int*)(ws + (224u << 10));       // 128 KB -> ends 352K
    float*          w1bs     = (float*)(ws + (352u << 10));              // 128 B
    float*          SU_p     = (float*)(ws + (356u << 10));              // 64 KB
    float*          SV_p     = (float*)(ws + (420u << 10));              // 64 KB -> ends 484K
    float*          U_p      = (float*)(ws + (512u << 10));              // 16 MB
    float*          V_p      = (float*)(ws + (512u << 10) + (16u << 20)); // 16 MB

    const float* xyz = (const float*)d_in[0];
    const float* pf  = (const float*)d_in[1];
    const float* w1  = (const float*)d_in[2];
    const float* b1  = (const float*)d_in[3];

    k_prep<<<31, 256, 0, stream>>>(w1, (const float*)d_in[6],
                                   w2T, w1aT, w1cT, w1bT, pooled_r, w1bs);
    k_pre<<<1024, 256, 0, stream>>>(xyz, pf, w1aT, w1cT, b1, U_p, V_p, SU_p, SV_p);
    k_main<<<4096, 512, 0, stream>>>(xyz, w1bT, w2T, U_p, V_p, SU_p, SV_p, w1bs,
                                     (const float*)d_in[4], (const float*)d_in[5],
                                     (const float*)d_in[7], (const float*)d_in[8],
                                     (const float*)d_in[9], pooled_r);
    k_final<<<4, 256, 0, stream>>>(pooled_r,
                                   (const float*)d_in[10], (const float*)d_in[11],
                                   (const float*)d_in[12], (const float*)d_in[13],
                                   (const float*)d_in[14], (const float*)d_in[15],
                                   (const float*)d_in[16], (const float*)d_in[17],
                                   (float*)d_out);
}

// Round 11
// 390.128 us; speedup vs baseline: 1.0693x; 1.0693x over previous
//
#include <hip/hip_runtime.h>
#include <hip/hip_bf16.h>
#include <math.h>

// GlobalSceneTokenizer fused pipeline, f32 in/out.
// R25 = exact revert to R23/R20 (verified optimum: total 385-390us across two
// independent runs; k_main 286-300us). Session converged.
// R24 post-mortem: LN1-mean factoring removed parallel VALU (VALUBusy
// 59.5->50.3) but replaced it with a SERIAL tid<128 dot + scattered SU/SV
// gathers between barriers -> k_main 286->316us. Lesson: redundant-but-
// parallel beats minimal-but-serial when the serial section sits between
// block-wide barriers.
// Final state: R18 factored stage-1 (U[j]=pf@w1a, V'[c]=absemb@w1c+b1 in
// k_pre, 1024 blocks/16 rows), k_main stage-1 = C-init gather(U)+V' + one
// K=32 rel MFMA, stage-2 K=256 pi-permuted, 128 rows 8 waves 2Mx4N,
// R19/R20 atomic-floor removal (32-replica pooled, LDS pre-reduce, separate
// 4-block k_final). Binding constraint: VALU-issue + dependency latency at
// the exactly-saturated 128-unified-reg / 16-wave-per-CU ceiling.
// Probed and rejected: 4-centers/block (R15 flat), wave-local no-barrier
// (R16 -2.4x), 32-wave occupancy (R17 -1.5x), VOP3P packing (R21 wrong,
// R22 net-negative), tail consolidation (R22 neutral), LN1-mean factoring
// (R24 -10%).

#define LN_EPS 1e-5f

typedef __attribute__((ext_vector_type(8))) short bf16x8;
typedef __attribute__((ext_vector_type(4))) float f32x4;
typedef __attribute__((ext_vector_type(2))) unsigned int u32x2;
typedef __attribute__((ext_vector_type(4))) unsigned int u32x4;

#if __has_builtin(__builtin_amdgcn_rcpf)
#define FRCP(x) __builtin_amdgcn_rcpf(x)
#else
#define FRCP(x) (1.0f / (x))
#endif

__device__ __forceinline__ unsigned short f2bf(float f) {
    unsigned int x = __float_as_uint(f);
    return (unsigned short)((x + 0x7FFFu + ((x >> 16) & 1u)) >> 16);  // RNE
}
__device__ __forceinline__ unsigned int pack2(float a, float b) {
    union { __hip_bfloat162 h; unsigned int u; } cvt;
    cvt.h = __float22bfloat162_rn(make_float2(a, b));
    return cvt.u;
}
__device__ __forceinline__ unsigned int fenc(float f) {
    unsigned int u = __float_as_uint(f);
    return (u & 0x80000000u) ? ~u : (u | 0x80000000u);
}
__device__ __forceinline__ float fdec(unsigned int u) {
    return __uint_as_float((u & 0x80000000u) ? (u & 0x7FFFFFFFu) : ~u);
}
__device__ __forceinline__ float gelu_fast(float x) {
    float x2 = x * x;
    float u = x * fmaf(0.0356774081f, x2, 0.7978845608f);
    float e = exp2f(u * -2.8853900818f);   // e^{-2u}
    float r = FRCP(e + 1.0f);              // sigma(2u)
    return x * r;
}
template<int CTRL>
__device__ __forceinline__ float dppadd(float s) {
    int v = __builtin_amdgcn_update_dpp(0, __float_as_int(s), CTRL, 0xF, 0xF, true);
    return s + __int_as_float(v);
}
__device__ __forceinline__ float rowsum16(float x) {
    x = dppadd<0x128>(x);   // ror:8
    x = dppadd<0x124>(x);   // ror:4
    x = dppadd<0x122>(x);   // ror:2
    x = dppadd<0x121>(x);   // ror:1
    return x;
}

// ---------------- K_prep ----------------------------------------------------
// blk 0..15 : w2T [n=256][k=256], k pi-permuted: pi(nt*16+lo)=lo*4+nt per 64-blk
// blk 16..19: w1aT [n=256][k=64]   (w1 rows 0..63, pf part)
// blk 20..27: w1cT [n=256][k=96]   (w1 rows 91..186, abs part)
// blk 28    : w1bT [n=256][k=32]   (w1 rows 64..90 rel part, pad 0)
// blk 29    : pooled_r init (32 replicas x 1024)
__global__ __launch_bounds__(256) void k_prep(
    const float* __restrict__ w1, const float* __restrict__ w2,
    unsigned short* __restrict__ w2T, unsigned short* __restrict__ w1aT,
    unsigned short* __restrict__ w1cT, unsigned short* __restrict__ w1bT,
    unsigned int* __restrict__ pooled_r)
{
    int t = threadIdx.x, blk = blockIdx.x;
    if (blk < 16) {                      // w2T: [n=256][k=256 permuted]
        __shared__ unsigned short tile[64][65];
        int tr = blk >> 2, tc = blk & 3;
        #pragma unroll
        for (int rr = 0; rr < 16; ++rr) {
            int kl = rr * 4 + (t >> 6), nl = t & 63;
            tile[kl][nl] = f2bf(w2[(size_t)(tr * 64 + kl) * 256 + tc * 64 + nl]);
        }
        __syncthreads();
        #pragma unroll
        for (int rr = 0; rr < 16; ++rr) {
            int nl = rr * 4 + (t >> 6), kp = t & 63;
            int kl = (kp & 3) * 16 + (kp >> 2);      // pi^-1
            w2T[(size_t)(tc * 64 + nl) * 256 + tr * 64 + kp] = tile[kl][nl];
        }
    } else if (blk < 20) {               // w1aT: [256][64]
        __shared__ unsigned short tile[64][65];
        int tc = blk - 16;
        #pragma unroll
        for (int rr = 0; rr < 16; ++rr) {
            int kl = rr * 4 + (t >> 6), nl = t & 63;
            tile[kl][nl] = f2bf(w1[(size_t)kl * 256 + tc * 64 + nl]);
        }
        __syncthreads();
        #pragma unroll
        for (int rr = 0; rr < 16; ++rr) {
            int nl = rr * 4 + (t >> 6), kl = t & 63;
            w1aT[(size_t)(tc * 64 + nl) * 64 + kl] = tile[kl][nl];
        }
    } else if (blk < 28) {               // w1cT: [256][96] from w1 rows 91..186
        __shared__ unsigned short tile[64][65];
        int idx = blk - 20;
        int tr2 = idx >> 2, tc = idx & 3;
        #pragma unroll
        for (int rr = 0; rr < 16; ++rr) {
            int kl = rr * 4 + (t >> 6), nl = t & 63;
            int k = tr2 * 64 + kl;
            float v = 0.f;
            if (k < 96) v = w1[(size_t)(91 + k) * 256 + tc * 64 + nl];
            tile[kl][nl] = f2bf(v);
        }
        __syncthreads();
        #pragma unroll
        for (int rr = 0; rr < 16; ++rr) {
            int nl = rr * 4 + (t >> 6), kl = t & 63;
            int k = tr2 * 64 + kl;
            if (k < 96)
                w1cT[(size_t)(tc * 64 + nl) * 96 + k] = tile[kl][nl];
        }
    } else if (blk == 28) {              // w1bT: [256][32], rel part
        int n = t;
        #pragma unroll
        for (int k = 0; k < 32; ++k) {
            unsigned short v = 0;
            if (k < 27) v = f2bf(w1[(size_t)(64 + k) * 256 + n]);
            w1bT[(size_t)n * 32 + k] = v;
        }
    } else {
        unsigned int idv = fenc(-1e19f);
        for (int q = t; q < 32768; q += 256) pooled_r[q] = idv;
    }
}

// ---------------- K_pre: U[p]=pf@w1a, V'[p]=absemb@w1c+b1 (pi-permuted f32) --
// 1024 blocks x 256 threads; 16 rows/block; wave = 16 rows x 64 cols (wvN=wv)
__global__ __launch_bounds__(256) void k_pre(
    const float* __restrict__ xyz, const float* __restrict__ pf,
    const unsigned short* __restrict__ w1aT, const unsigned short* __restrict__ w1cT,
    const float* __restrict__ b1,
    float* __restrict__ U_p, float* __restrict__ V_p)
{
    __shared__ __align__(16) unsigned short ptile[16 * 72];    // pf bf16
    __shared__ __align__(16) unsigned short etile[16 * 104];   // abs emb bf16
    int tid = threadIdx.x, wv = tid >> 6, lane = tid & 63;
    int lo16 = lane & 15, quad = lane >> 4;
    int rows0 = blockIdx.x * 16;

    // stage pf (16 rows x 64 cols): thread = (row, 4-float seg)
    {
        int r = tid >> 4, seg = tid & 15;
        f32x4 v = *(const f32x4*)(pf + (size_t)(rows0 + r) * 64 + seg * 4);
        u32x2 o; o.x = pack2(v.x, v.y); o.y = pack2(v.z, v.w);
        *(u32x2*)&ptile[r * 72 + seg * 4] = o;
    }
    // stage abs sin-emb (16 rows x 48 pairs = 768 items); 3 items/thread
    #pragma unroll
    for (int q = 0; q < 3; ++q) {
        int item = q * 256 + tid;
        int r = item / 48, pr = item - 48 * r;
        float vals[2];
        #pragma unroll
        for (int qq = 0; qq < 2; ++qq) {
            int cc = pr * 2 + qq;
            int a = cc >> 5, wI = cc & 31;
            int jf = (wI < 16) ? wI : (wI - 16);
            float coord = xyz[(size_t)(rows0 + r) * 3 + a];
            float fr = __expf(-0.61402269146507894f * (float)jf);
            float ang = coord * fr;
            vals[qq] = (wI < 16) ? __sinf(ang) : __cosf(ang);
        }
        *(unsigned int*)&etile[r * 104 + 2 * pr] = pack2(vals[0], vals[1]);
    }
    __syncthreads();

    // U GEMM: K=64, C-init 0; wave covers cols wv*64..+64 of its 16 rows
    f32x4 acc[4];
    #pragma unroll
    for (int nt = 0; nt < 4; ++nt) acc[nt] = (f32x4){0.f, 0.f, 0.f, 0.f};
    #pragma unroll
    for (int ks = 0; ks < 2; ++ks) {
        bf16x8 afr = *(const bf16x8*)&ptile[lo16 * 72 + ks * 32 + quad * 8];
        #pragma unroll
        for (int nt = 0; nt < 4; ++nt) {
            int n = wv * 64 + nt * 16 + lo16;
            bf16x8 bfr = *(const bf16x8*)&w1aT[(size_t)n * 64 + ks * 32 + quad * 8];
            acc[nt] = __builtin_amdgcn_mfma_f32_16x16x32_bf16(afr, bfr, acc[nt], 0, 0, 0);
        }
    }
    #pragma unroll
    for (int reg = 0; reg < 4; ++reg) {
        f32x4 o = {acc[0][reg], acc[1][reg], acc[2][reg], acc[3][reg]};
        *(f32x4*)&U_p[(size_t)(rows0 + quad * 4 + reg) * 256 + wv * 64 + lo16 * 4] = o;
    }

    // V GEMM: K=96, C-init = b1 (folded)
    {
        float b1f[4];
        #pragma unroll
        for (int nt = 0; nt < 4; ++nt) b1f[nt] = b1[wv * 64 + nt * 16 + lo16];
        #pragma unroll
        for (int nt = 0; nt < 4; ++nt)
            #pragma unroll
            for (int reg = 0; reg < 4; ++reg) acc[nt][reg] = b1f[nt];
    }
    #pragma unroll
    for (int ks = 0; ks < 3; ++ks) {
        bf16x8 afr = *(const bf16x8*)&etile[lo16 * 104 + ks * 32 + quad * 8];
        #pragma unroll
        for (int nt = 0; nt < 4; ++nt) {
            int n = wv * 64 + nt * 16 + lo16;
            bf16x8 bfr = *(const bf16x8*)&w1cT[(size_t)n * 96 + ks * 32 + quad * 8];
            acc[nt] = __builtin_amdgcn_mfma_f32_16x16x32_bf16(afr, bfr, acc[nt], 0, 0, 0);
        }
    }
    #pragma unroll
    for (int reg = 0; reg < 4; ++reg) {
        f32x4 o = {acc[0][reg], acc[1][reg], acc[2][reg], acc[3][reg]};
        *(f32x4*)&V_p[(size_t)(rows0 + quad * 4 + reg) * 256 + wv * 64 + lo16 * 4] = o;
    }
}

// ---------------- K_main ---------------------------------------------------
__global__ __launch_bounds__(512, 4) void k_main(
    const float* __restrict__ xyz,
    const unsigned short* __restrict__ w1bT, const unsigned short* __restrict__ w2T,
    const float* __restrict__ U_p, const float* __restrict__ V_p,
    const float* __restrict__ g1, const float* __restrict__ be1,
    const float* __restrict__ b2, const float* __restrict__ g2,
    const float* __restrict__ be2,
    unsigned int* __restrict__ pooled_r)
{
    // rels (128 x 32+8, stride 40) unioned with h1s (128 x 256+8, stride 264)
    __shared__ __align__(16) unsigned short smem[128 * 264];   // 67584 B
    __shared__ unsigned long long bmask[4][64];
    __shared__ int   idxs[128];
    __shared__ float ctr[4][3];
    __shared__ float reds[128][4][2];
    __shared__ float musig[128][2];
    __shared__ unsigned int pool_s[256];
    unsigned short* rels = smem;  // stride 40 (dead once stage-1 MFMAs done)
    unsigned short* h1s  = smem;  // stride 264 (k-permuted within 64-blocks)

    const int N = 4096;
    int tid = threadIdx.x, wv = tid >> 6, lane = tid & 63;
    int lo16 = lane & 15, quad = lane >> 4;
    int wvM = wv >> 2, wvN = wv & 3;           // 2(M) x 4(N) wave grid
    int b = blockIdx.x & 3;                    // batch-major for L2 locality
    int i0 = (blockIdx.x >> 2) * 4;
    int rep = (blockIdx.x >> 2) & 31;          // pooled replica
    size_t base = (size_t)b * N;
    const float* xb = xyz + base * 3;

    // hoisted: rel-part stage-1 weights (independent of LDS)
    bf16x8 bfrR[4];
    #pragma unroll
    for (int nt = 0; nt < 4; ++nt) {
        int n = wvN * 64 + nt * 16 + lo16;
        bfrR[nt] = *(const bf16x8*)&w1bT[(size_t)n * 32 + quad * 8];
    }

    // P0a: centers + pool_s init
    if (tid < 256) pool_s[tid] = fenc(-1e19f);
    if (tid < 12) { int p = tid / 3, a = tid - 3 * p; ctr[p][a] = xb[(i0 + p) * 3 + a]; }
    // exact fp32 threshold: largest float <= (double)0.16*0.16  (validated R9)
    const double r2d = 0.16 * 0.16;
    float T = (float)r2d;
    if ((double)T > r2d) T = __uint_as_float(__float_as_uint(T) - 1u);
    // P0c phase A: each wave scans 8 chunks, all 4 centers per point load
    {
        f32x4 cA = *(const f32x4*)(xb + (size_t)i0 * 3);
        f32x4 cB = *(const f32x4*)(xb + (size_t)i0 * 3 + 4);
        f32x4 cC = *(const f32x4*)(xb + (size_t)i0 * 3 + 8);
        float cx0 = cA.x, cy0 = cA.y, cz0 = cA.z;
        float cx1 = cA.w, cy1 = cB.x, cz1 = cB.y;
        float cx2 = cB.z, cy2 = cB.w, cz2 = cC.x;
        float cx3 = cC.y, cy3 = cC.z, cz3 = cC.w;
        #pragma unroll 2
        for (int i = 0; i < 8; ++i) {
            int chunk = wv * 8 + i;
            int j = chunk * 64 + lane;
            const float* pp = xb + (size_t)j * 3;
            float px = pp[0], py = pp[1], pz = pp[2];
            float dx0 = __fsub_rn(px, cx0), dy0 = __fsub_rn(py, cy0), dz0 = __fsub_rn(pz, cz0);
            float sq0 = __fadd_rn(__fadd_rn(__fmul_rn(dx0, dx0), __fmul_rn(dy0, dy0)),
                                  __fmul_rn(dz0, dz0));
            unsigned long long m0 = __ballot(sq0 <= T);
            float dx1 = __fsub_rn(px, cx1), dy1 = __fsub_rn(py, cy1), dz1 = __fsub_rn(pz, cz1);
            float sq1 = __fadd_rn(__fadd_rn(__fmul_rn(dx1, dx1), __fmul_rn(dy1, dy1)),
                                  __fmul_rn(dz1, dz1));
            unsigned long long m1 = __ballot(sq1 <= T);
            float dx2 = __fsub_rn(px, cx2), dy2 = __fsub_rn(py, cy2), dz2 = __fsub_rn(pz, cz2);
            float sq2 = __fadd_rn(__fadd_rn(__fmul_rn(dx2, dx2), __fmul_rn(dy2, dy2)),
                                  __fmul_rn(dz2, dz2));
            unsigned long long m2 = __ballot(sq2 <= T);
            float dx3 = __fsub_rn(px, cx3), dy3 = __fsub_rn(py, cy3), dz3 = __fsub_rn(pz, cz3);
            float sq3 = __fadd_rn(__fadd_rn(__fmul_rn(dx3, dx3), __fmul_rn(dy3, dy3)),
                                  __fmul_rn(dz3, dz3));
            unsigned long long m3 = __ballot(sq3 <= T);
            if (lane == 0) {
                bmask[0][chunk] = m0; bmask[1][chunk] = m1;
                bmask[2][chunk] = m2; bmask[3][chunk] = m3;
            }
        }
    }
    __syncthreads();
    // P0c phase B: waves 0..3 select first 32 by ascending index (one center each)
    if (wv < 4) {
        int p = wv;
        unsigned long long m = bmask[p][lane];
        int c = __popcll(m);
        int inc = c;
        #pragma unroll
        for (int d = 1; d <= 32; d <<= 1) {
            int v = __shfl_up(inc, d);
            if (lane >= d) inc += v;
        }
        int exc = inc - c;
        int total = __shfl(inc, 63);
        unsigned long long lm = __ballot(m != 0ull);
        int fl = __ffsll(lm) - 1;                       // total>=1 (center in ball)
        unsigned long long mf = (unsigned long long)__shfl((long long)m, fl);
        int firstj = fl * 64 + __ffsll(mf) - 1;
        unsigned long long mm = m;
        int t = 0;
        while (mm != 0ull && (exc + t) < 32) {
            int bpos = __ffsll(mm) - 1;
            idxs[p * 32 + exc + t] = lane * 64 + bpos;
            mm &= mm - 1; ++t;
        }
        if (lane >= total && lane < 32) idxs[p * 32 + lane] = firstj;  // pad
    }
    __syncthreads();

    // P1b: rel xyz (cols 0..2) + rel emb (3..26) + zeros (27..31)
    {
        int r = tid & 127, part = tid >> 7;
        int p = r >> 5;
        int j = idxs[r];
        float rx = xb[j * 3]     - ctr[p][0];
        float ry = xb[j * 3 + 1] - ctr[p][1];
        float rz = xb[j * 3 + 2] - ctr[p][2];
        unsigned short* arow = &rels[r * 40];
        if (part == 0) {
            *(unsigned int*)&arow[0] = pack2(rx, ry);
            arow[2] = f2bf(rz);
            arow[27] = 0;
            *(u32x2*)&arow[28] = (u32x2){0u, 0u};
        } else {
            int a = part - 1;
            float cv = (a == 0) ? rx : ((a == 1) ? ry : rz);
            const float fr4[4] = {1.f, 0.046415888336127774f,
                                  0.0021544346900318843f, 1e-4f};  // 10000^(-j/3)
            float sn[4], cs[4];
            #pragma unroll
            for (int tt = 0; tt < 4; ++tt) {
                float ang = cv * fr4[tt];
                sn[tt] = __sinf(ang); cs[tt] = __cosf(ang);
            }
            arow[3 + a * 8 + 0] = f2bf(sn[0]); arow[3 + a * 8 + 1] = f2bf(sn[1]);
            arow[3 + a * 8 + 2] = f2bf(sn[2]); arow[3 + a * 8 + 3] = f2bf(sn[3]);
            arow[3 + a * 8 + 4] = f2bf(cs[0]); arow[3 + a * 8 + 5] = f2bf(cs[1]);
            arow[3 + a * 8 + 6] = f2bf(cs[2]); arow[3 + a * 8 + 7] = f2bf(cs[3]);
        }
    }
    __syncthreads();

    // P2: C-init = U[j] + V'[c]  (b1 folded into V'); then rel MFMA K=32
    const int arow0 = wvM * 64;
    f32x4 acc[4][4];
    #pragma unroll
    for (int mt = 0; mt < 4; ++mt) {
        int cl = wvM * 2 + (mt >> 1);   // center of rows [arow0+mt*16, +16)
        f32x4 vv = *(const f32x4*)&V_p[(size_t)(base + i0 + cl) * 256 + wvN * 64 + lo16 * 4];
        #pragma unroll
        for (int reg = 0; reg < 4; ++reg) {
            int r = arow0 + mt * 16 + quad * 4 + reg;
            int j = idxs[r];
            f32x4 uu = *(const f32x4*)&U_p[(size_t)(base + j) * 256 + wvN * 64 + lo16 * 4];
            #pragma unroll
            for (int nt = 0; nt < 4; ++nt) acc[mt][nt][reg] = uu[nt] + vv[nt];
        }
    }
    #pragma unroll
    for (int mt = 0; mt < 4; ++mt) {
        bf16x8 afr = *(const bf16x8*)&rels[(arow0 + mt * 16 + lo16) * 40 + quad * 8];
        #pragma unroll
        for (int nt = 0; nt < 4; ++nt)
            acc[mt][nt] = __builtin_amdgcn_mfma_f32_16x16x32_bf16(
                afr, bfrR[nt], acc[mt][nt], 0, 0, 0);
    }

    // P3: LN1 stats (DPP + cross-wave reds) -> gelu -> h1s (pi-packed b64)
    #pragma unroll
    for (int mt = 0; mt < 4; ++mt) {
        #pragma unroll
        for (int reg = 0; reg < 4; ++reg) {
            float s1 = 0.f, s2 = 0.f;
            #pragma unroll
            for (int nt = 0; nt < 4; ++nt) { float v = acc[mt][nt][reg]; s1 += v; s2 = fmaf(v, v, s2); }
            s1 = rowsum16(s1); s2 = rowsum16(s2);
            if (lo16 == 0) {
                int r = arow0 + mt * 16 + quad * 4 + reg;
                reds[r][wvN][0] = s1; reds[r][wvN][1] = s2;
            }
        }
    }
    __syncthreads();   // reds ready; all waves done reading rels
    if (tid < 128) {
        int r = tid;
        float s1 = reds[r][0][0] + reds[r][1][0] + reds[r][2][0] + reds[r][3][0];
        float s2 = reds[r][0][1] + reds[r][1][1] + reds[r][2][1] + reds[r][3][1];
        float mu = s1 * (1.f / 256.f);
        float var = fmaxf(s2 * (1.f / 256.f) - mu * mu, 0.f);
        musig[r][0] = mu; musig[r][1] = rsqrtf(var + LN_EPS);
    }
    __syncthreads();
    {
        float g1f[4], be1f[4];
        #pragma unroll
        for (int nt = 0; nt < 4; ++nt) {
            int n = wvN * 64 + nt * 16 + lo16;
            g1f[nt] = g1[n]; be1f[nt] = be1[n];
        }
        #pragma unroll
        for (int mt = 0; mt < 4; ++mt) {
            #pragma unroll
            for (int reg = 0; reg < 4; ++reg) {
                int r = arow0 + mt * 16 + quad * 4 + reg;
                float mu = musig[r][0], rs = musig[r][1];
                float v0 = gelu_fast(fmaf((acc[mt][0][reg] - mu) * rs, g1f[0], be1f[0]));
                float v1 = gelu_fast(fmaf((acc[mt][1][reg] - mu) * rs, g1f[1], be1f[1]));
                float v2 = gelu_fast(fmaf((acc[mt][2][reg] - mu) * rs, g1f[2], be1f[2]));
                float v3 = gelu_fast(fmaf((acc[mt][3][reg] - mu) * rs, g1f[3], be1f[3]));
                u32x2 w; w.x = pack2(v0, v1); w.y = pack2(v2, v3);
                *(u32x2*)&h1s[r * 264 + wvN * 64 + lo16 * 4] = w;   // pi(n)=lo16*4+nt
            }
        }
    }
    __syncthreads();   // h1s ready

    // P4: stage-2 MFMA K=256 (pi-permuted; w2T matches); C-init = b2
    {
        float b2f[4];
        #pragma unroll
        for (int nt = 0; nt < 4; ++nt) b2f[nt] = b2[wvN * 64 + nt * 16 + lo16];
        #pragma unroll
        for (int mt = 0; mt < 4; ++mt)
            #pragma unroll
            for (int nt = 0; nt < 4; ++nt)
                #pragma unroll
                for (int reg = 0; reg < 4; ++reg) acc[mt][nt][reg] = b2f[nt];
    }
    for (int ks = 0; ks < 8; ++ks) {
        bf16x8 bfr[4], afr[4];
        #pragma unroll
        for (int nt = 0; nt < 4; ++nt) {
            int n = wvN * 64 + nt * 16 + lo16;
            bfr[nt] = *(const bf16x8*)&w2T[(size_t)n * 256 + ks * 32 + quad * 8];
        }
        #pragma unroll
        for (int mt = 0; mt < 4; ++mt)
            afr[mt] = *(const bf16x8*)&h1s[(arow0 + mt * 16 + lo16) * 264 + ks * 32 + quad * 8];
        #pragma unroll
        for (int mt = 0; mt < 4; ++mt)
            #pragma unroll
            for (int nt = 0; nt < 4; ++nt)
                acc[mt][nt] = __builtin_amdgcn_mfma_f32_16x16x32_bf16(
                    afr[mt], bfr[nt], acc[mt][nt], 0, 0, 0);
    }

    // P5: LN2 stats (DPP + reds), normalize, col-max -> LDS pool_s -> global
    {
        #pragma unroll
        for (int mt = 0; mt < 4; ++mt) {
            #pragma unroll
            for (int reg = 0; reg < 4; ++reg) {
                float s1 = 0.f, s2 = 0.f;
                #pragma unroll
                for (int nt = 0; nt < 4; ++nt) { float v = acc[mt][nt][reg]; s1 += v; s2 = fmaf(v, v, s2); }
                s1 = rowsum16(s1); s2 = rowsum16(s2);
                if (lo16 == 0) {
                    int r = arow0 + mt * 16 + quad * 4 + reg;
                    reds[r][wvN][0] = s1; reds[r][wvN][1] = s2;
                }
            }
        }
        __syncthreads();
        if (tid < 128) {
            int r = tid;
            float s1 = reds[r][0][0] + reds[r][1][0] + reds[r][2][0] + reds[r][3][0];
            float s2 = reds[r][0][1] + reds[r][1][1] + reds[r][2][1] + reds[r][3][1];
            float mu = s1 * (1.f / 256.f);
            float var = fmaxf(s2 * (1.f / 256.f) - mu * mu, 0.f);
            musig[r][0] = mu; musig[r][1] = rsqrtf(var + LN_EPS);
        }
        __syncthreads();

        float g2f[4], be2f[4];
        #pragma unroll
        for (int nt = 0; nt < 4; ++nt) {
            int n = wvN * 64 + nt * 16 + lo16;
            g2f[nt] = g2[n]; be2f[nt] = be2[n];
        }
        float mx[4] = {-1e30f, -1e30f, -1e30f, -1e30f};
        #pragma unroll
        for (int mt = 0; mt < 4; ++mt) {
            #pragma unroll
            for (int reg = 0; reg < 4; ++reg) {
                int r = arow0 + mt * 16 + quad * 4 + reg;
                float mu = musig[r][0], rs = musig[r][1];
                #pragma unroll
                for (int nt = 0; nt < 4; ++nt) {
                    float v = fmaf((acc[mt][nt][reg] - mu) * rs, g2f[nt], be2f[nt]);
                    mx[nt] = fmaxf(mx[nt], v);
                }
            }
        }
        #pragma unroll
        for (int nt = 0; nt < 4; ++nt) {
            mx[nt] = fmaxf(mx[nt], __shfl_xor(mx[nt], 16));
            mx[nt] = fmaxf(mx[nt], __shfl_xor(mx[nt], 32));
        }
        if (quad == 0) {
            #pragma unroll
            for (int nt = 0; nt < 4; ++nt)
                atomicMax(&pool_s[wvN * 64 + nt * 16 + lo16], fenc(mx[nt]));
        }
    }
    // flush pool_s to this block's replica (256 coalesced atomics)
    __syncthreads();
    if (tid < 256)
        atomicMax(pooled_r + rep * 1024 + b * 256 + tid, pool_s[tid]);
}

// ---------------- K_final: replica max-reduce + final MLPs ------------------
// 4 blocks (one per batch) x 256 threads; thread owns output col c = tid.
__global__ __launch_bounds__(256) void k_final(
    const unsigned int* __restrict__ pooled_r,
    const float* __restrict__ pw1, const float* __restrict__ pb1,
    const float* __restrict__ pg1, const float* __restrict__ pbe1,
    const float* __restrict__ pw2, const float* __restrict__ pb2,
    const float* __restrict__ pg2, const float* __restrict__ pbe2,
    float* __restrict__ out)
{
    __shared__ float xw[256], xh[256];
    __shared__ float lred[2][4];
    int tid = threadIdx.x, wv = tid >> 6;
    int bb = blockIdx.x;

    // replica max-reduce for this thread's column
    {
        unsigned int mv = pooled_r[bb * 256 + tid];
        #pragma unroll
        for (int r = 1; r < 32; ++r) {
            unsigned int v = pooled_r[r * 1024 + bb * 256 + tid];
            mv = (v > mv) ? v : mv;
        }
        xw[tid] = fdec(mv);
    }
    __syncthreads();

    // MLP1: a1[c] = pb1[c] + sum_k xw[k]*pw1[k][c]
    float a1 = pb1[tid];
    #pragma unroll 8
    for (int k = 0; k < 256; ++k)
        a1 = fmaf(xw[k], pw1[(size_t)k * 256 + tid], a1);
    // LN over cols (4-wave reduce)
    float s1 = a1, s2 = a1 * a1;
    s1 = rowsum16(s1); s2 = rowsum16(s2);
    s1 += __shfl_xor(s1, 16); s2 += __shfl_xor(s2, 16);
    s1 += __shfl_xor(s1, 32); s2 += __shfl_xor(s2, 32);
    if ((tid & 63) == 0) { lred[0][wv] = s1; lred[1][wv] = s2; }
    __syncthreads();
    s1 = lred[0][0] + lred[0][1] + lred[0][2] + lred[0][3];
    s2 = lred[1][0] + lred[1][1] + lred[1][2] + lred[1][3];
    float mu = s1 * (1.f / 256.f);
    float rs = rsqrtf(fmaxf(s2 * (1.f / 256.f) - mu * mu, 0.f) + LN_EPS);
    xh[tid] = gelu_fast(fmaf((a1 - mu) * rs, pg1[tid], pbe1[tid]));
    __syncthreads();

    // MLP2
    float a2 = pb2[tid];
    #pragma unroll 8
    for (int k = 0; k < 256; ++k)
        a2 = fmaf(xh[k], pw2[(size_t)k * 256 + tid], a2);
    s1 = a2; s2 = a2 * a2;
    s1 = rowsum16(s1); s2 = rowsum16(s2);
    s1 += __shfl_xor(s1, 16); s2 += __shfl_xor(s2, 16);
    s1 += __shfl_xor(s1, 32); s2 += __shfl_xor(s2, 32);
    if ((tid & 63) == 0) { lred[0][wv] = s1; lred[1][wv] = s2; }
    __syncthreads();
    s1 = lred[0][0] + lred[0][1] + lred[0][2] + lred[0][3];
    s2 = lred[1][0] + lred[1][1] + lred[1][2] + lred[1][3];
    mu = s1 * (1.f / 256.f);
    rs = rsqrtf(fmaxf(s2 * (1.f / 256.f) - mu * mu, 0.f) + LN_EPS);
    out[bb * 256 + tid] = fmaf((a2 - mu) * rs, pg2[tid], pbe2[tid]);
}

// ---------------- launch ---------------------------------------------------
extern "C" void kernel_launch(void* const* d_in, const int* in_sizes, int n_in,
                              void* d_out, int out_size, void* d_ws, size_t ws_size,
                              hipStream_t stream)
{
    char* ws = (char*)d_ws;
    unsigned short* w2T      = (unsigned short*)ws;                      // 128 KB
    unsigned short* w1aT     = (unsigned short*)(ws + (128u << 10));     // 32 KB
    unsigned short* w1cT     = (unsigned short*)(ws + (160u << 10));     // 48 KB
    unsigned short* w1bT     = (unsigned short*)(ws + (208u << 10));     // 16 KB
    unsigned int*   pooled_r = (unsigned int*)(ws + (224u << 10));       // 128 KB
    float*          U_p      = (float*)(ws + (512u << 10));              // 16 MB
    float*          V_p      = (float*)(ws + (512u << 10) + (16u << 20)); // 16 MB

    const float* xyz = (const float*)d_in[0];
    const float* pf  = (const float*)d_in[1];
    const float* w1  = (const float*)d_in[2];
    const float* b1  = (const float*)d_in[3];

    k_prep<<<30, 256, 0, stream>>>(w1, (const float*)d_in[6],
                                   w2T, w1aT, w1cT, w1bT, pooled_r);
    k_pre<<<1024, 256, 0, stream>>>(xyz, pf, w1aT, w1cT, b1, U_p, V_p);
    k_main<<<4096, 512, 0, stream>>>(xyz, w1bT, w2T, U_p, V_p,
                                     (const float*)d_in[4], (const float*)d_in[5],
                                     (const float*)d_in[7], (const float*)d_in[8],
                                     (const float*)d_in[9], pooled_r);
    k_final<<<4, 256, 0, stream>>>(pooled_r,
                                   (const float*)d_in[10], (const float*)d_in[11],
                                   (const float*)d_in[12], (const float*)d_in[13],
                                   (const float*)d_in[14], (const float*)d_in[15],
                                   (const float*)d_in[16], (const float*)d_in[17],
                                   (float*)d_out);
}

// Round 13
// 387.998 us; speedup vs baseline: 1.0752x; 1.0055x over previous
//
#include <hip/hip_runtime.h>
#include <hip/hip_bf16.h>
#include <math.h>

// GlobalSceneTokenizer fused pipeline, f32 in/out.
// R27 = R26 resubmitted verbatim (R26's bench was an infrastructure failure:
// "MI355X container failed twice" — no compile/correctness/perf data).
// R26 = R25/R20 optimum + musig barrier elimination (applying R24's lesson in
// the profitable direction: redundant-but-parallel beats minimal-but-serial
// between block-wide barriers). The two `if (tid<128)` musig phases in P3/P5
// each cost one extra __syncthreads + an idle phase for 3/4 waves. Replaced
// by per-wave redundant stats: lane L computes row arow0+L from reds (same
// expression, same inputs -> BIT-IDENTICAL values across the 4 racing wvN
// waves; benign race), and each wave writes every musig row it later reads,
// so same-wave in-order DS semantics remove the second barrier. Barriers
// 9 -> 7. absmax must stay exactly 0.015625 (canary for race benignity).
// Everything else byte-identical to R25/R23/R20: R18 factored stage-1
// (U[j]=pf@w1a, V'[c]=absemb@w1c+b1 in k_pre), k_main stage-1 = C-init
// gather(U)+V' + one K=32 rel MFMA, stage-2 K=256 pi-permuted, 128 rows
// 8 waves 2Mx4N, R19/R20 atomic-floor removal (32-replica pooled, LDS
// pre-reduce, separate 4-block k_final).

#define LN_EPS 1e-5f

typedef __attribute__((ext_vector_type(8))) short bf16x8;
typedef __attribute__((ext_vector_type(4))) float f32x4;
typedef __attribute__((ext_vector_type(2))) unsigned int u32x2;
typedef __attribute__((ext_vector_type(4))) unsigned int u32x4;

#if __has_builtin(__builtin_amdgcn_rcpf)
#define FRCP(x) __builtin_amdgcn_rcpf(x)
#else
#define FRCP(x) (1.0f / (x))
#endif

__device__ __forceinline__ unsigned short f2bf(float f) {
    unsigned int x = __float_as_uint(f);
    return (unsigned short)((x + 0x7FFFu + ((x >> 16) & 1u)) >> 16);  // RNE
}
__device__ __forceinline__ unsigned int pack2(float a, float b) {
    union { __hip_bfloat162 h; unsigned int u; } cvt;
    cvt.h = __float22bfloat162_rn(make_float2(a, b));
    return cvt.u;
}
__device__ __forceinline__ unsigned int fenc(float f) {
    unsigned int u = __float_as_uint(f);
    return (u & 0x80000000u) ? ~u : (u | 0x80000000u);
}
__device__ __forceinline__ float fdec(unsigned int u) {
    return __uint_as_float((u & 0x80000000u) ? (u & 0x7FFFFFFFu) : ~u);
}
__device__ __forceinline__ float gelu_fast(float x) {
    float x2 = x * x;
    float u = x * fmaf(0.0356774081f, x2, 0.7978845608f);
    float e = exp2f(u * -2.8853900818f);   // e^{-2u}
    float r = FRCP(e + 1.0f);              // sigma(2u)
    return x * r;
}
template<int CTRL>
__device__ __forceinline__ float dppadd(float s) {
    int v = __builtin_amdgcn_update_dpp(0, __float_as_int(s), CTRL, 0xF, 0xF, true);
    return s + __int_as_float(v);
}
__device__ __forceinline__ float rowsum16(float x) {
    x = dppadd<0x128>(x);   // ror:8
    x = dppadd<0x124>(x);   // ror:4
    x = dppadd<0x122>(x);   // ror:2
    x = dppadd<0x121>(x);   // ror:1
    return x;
}

// ---------------- K_prep ----------------------------------------------------
// blk 0..15 : w2T [n=256][k=256], k pi-permuted: pi(nt*16+lo)=lo*4+nt per 64-blk
// blk 16..19: w1aT [n=256][k=64]   (w1 rows 0..63, pf part)
// blk 20..27: w1cT [n=256][k=96]   (w1 rows 91..186, abs part)
// blk 28    : w1bT [n=256][k=32]   (w1 rows 64..90 rel part, pad 0)
// blk 29    : pooled_r init (32 replicas x 1024)
__global__ __launch_bounds__(256) void k_prep(
    const float* __restrict__ w1, const float* __restrict__ w2,
    unsigned short* __restrict__ w2T, unsigned short* __restrict__ w1aT,
    unsigned short* __restrict__ w1cT, unsigned short* __restrict__ w1bT,
    unsigned int* __restrict__ pooled_r)
{
    int t = threadIdx.x, blk = blockIdx.x;
    if (blk < 16) {                      // w2T: [n=256][k=256 permuted]
        __shared__ unsigned short tile[64][65];
        int tr = blk >> 2, tc = blk & 3;
        #pragma unroll
        for (int rr = 0; rr < 16; ++rr) {
            int kl = rr * 4 + (t >> 6), nl = t & 63;
            tile[kl][nl] = f2bf(w2[(size_t)(tr * 64 + kl) * 256 + tc * 64 + nl]);
        }
        __syncthreads();
        #pragma unroll
        for (int rr = 0; rr < 16; ++rr) {
            int nl = rr * 4 + (t >> 6), kp = t & 63;
            int kl = (kp & 3) * 16 + (kp >> 2);      // pi^-1
            w2T[(size_t)(tc * 64 + nl) * 256 + tr * 64 + kp] = tile[kl][nl];
        }
    } else if (blk < 20) {               // w1aT: [256][64]
        __shared__ unsigned short tile[64][65];
        int tc = blk - 16;
        #pragma unroll
        for (int rr = 0; rr < 16; ++rr) {
            int kl = rr * 4 + (t >> 6), nl = t & 63;
            tile[kl][nl] = f2bf(w1[(size_t)kl * 256 + tc * 64 + nl]);
        }
        __syncthreads();
        #pragma unroll
        for (int rr = 0; rr < 16; ++rr) {
            int nl = rr * 4 + (t >> 6), kl = t & 63;
            w1aT[(size_t)(tc * 64 + nl) * 64 + kl] = tile[kl][nl];
        }
    } else if (blk < 28) {               // w1cT: [256][96] from w1 rows 91..186
        __shared__ unsigned short tile[64][65];
        int idx = blk - 20;
        int tr2 = idx >> 2, tc = idx & 3;
        #pragma unroll
        for (int rr = 0; rr < 16; ++rr) {
            int kl = rr * 4 + (t >> 6), nl = t & 63;
            int k = tr2 * 64 + kl;
            float v = 0.f;
            if (k < 96) v = w1[(size_t)(91 + k) * 256 + tc * 64 + nl];
            tile[kl][nl] = f2bf(v);
        }
        __syncthreads();
        #pragma unroll
        for (int rr = 0; rr < 16; ++rr) {
            int nl = rr * 4 + (t >> 6), kl = t & 63;
            int k = tr2 * 64 + kl;
            if (k < 96)
                w1cT[(size_t)(tc * 64 + nl) * 96 + k] = tile[kl][nl];
        }
    } else if (blk == 28) {              // w1bT: [256][32], rel part
        int n = t;
        #pragma unroll
        for (int k = 0; k < 32; ++k) {
            unsigned short v = 0;
            if (k < 27) v = f2bf(w1[(size_t)(64 + k) * 256 + n]);
            w1bT[(size_t)n * 32 + k] = v;
        }
    } else {
        unsigned int idv = fenc(-1e19f);
        for (int q = t; q < 32768; q += 256) pooled_r[q] = idv;
    }
}

// ---------------- K_pre: U[p]=pf@w1a, V'[p]=absemb@w1c+b1 (pi-permuted f32) --
// 1024 blocks x 256 threads; 16 rows/block; wave = 16 rows x 64 cols (wvN=wv)
__global__ __launch_bounds__(256) void k_pre(
    const float* __restrict__ xyz, const float* __restrict__ pf,
    const unsigned short* __restrict__ w1aT, const unsigned short* __restrict__ w1cT,
    const float* __restrict__ b1,
    float* __restrict__ U_p, float* __restrict__ V_p)
{
    __shared__ __align__(16) unsigned short ptile[16 * 72];    // pf bf16
    __shared__ __align__(16) unsigned short etile[16 * 104];   // abs emb bf16
    int tid = threadIdx.x, wv = tid >> 6, lane = tid & 63;
    int lo16 = lane & 15, quad = lane >> 4;
    int rows0 = blockIdx.x * 16;

    // stage pf (16 rows x 64 cols): thread = (row, 4-float seg)
    {
        int r = tid >> 4, seg = tid & 15;
        f32x4 v = *(const f32x4*)(pf + (size_t)(rows0 + r) * 64 + seg * 4);
        u32x2 o; o.x = pack2(v.x, v.y); o.y = pack2(v.z, v.w);
        *(u32x2*)&ptile[r * 72 + seg * 4] = o;
    }
    // stage abs sin-emb (16 rows x 48 pairs = 768 items); 3 items/thread
    #pragma unroll
    for (int q = 0; q < 3; ++q) {
        int item = q * 256 + tid;
        int r = item / 48, pr = item - 48 * r;
        float vals[2];
        #pragma unroll
        for (int qq = 0; qq < 2; ++qq) {
            int cc = pr * 2 + qq;
            int a = cc >> 5, wI = cc & 31;
            int jf = (wI < 16) ? wI : (wI - 16);
            float coord = xyz[(size_t)(rows0 + r) * 3 + a];
            float fr = __expf(-0.61402269146507894f * (float)jf);
            float ang = coord * fr;
            vals[qq] = (wI < 16) ? __sinf(ang) : __cosf(ang);
        }
        *(unsigned int*)&etile[r * 104 + 2 * pr] = pack2(vals[0], vals[1]);
    }
    __syncthreads();

    // U GEMM: K=64, C-init 0; wave covers cols wv*64..+64 of its 16 rows
    f32x4 acc[4];
    #pragma unroll
    for (int nt = 0; nt < 4; ++nt) acc[nt] = (f32x4){0.f, 0.f, 0.f, 0.f};
    #pragma unroll
    for (int ks = 0; ks < 2; ++ks) {
        bf16x8 afr = *(const bf16x8*)&ptile[lo16 * 72 + ks * 32 + quad * 8];
        #pragma unroll
        for (int nt = 0; nt < 4; ++nt) {
            int n = wv * 64 + nt * 16 + lo16;
            bf16x8 bfr = *(const bf16x8*)&w1aT[(size_t)n * 64 + ks * 32 + quad * 8];
            acc[nt] = __builtin_amdgcn_mfma_f32_16x16x32_bf16(afr, bfr, acc[nt], 0, 0, 0);
        }
    }
    #pragma unroll
    for (int reg = 0; reg < 4; ++reg) {
        f32x4 o = {acc[0][reg], acc[1][reg], acc[2][reg], acc[3][reg]};
        *(f32x4*)&U_p[(size_t)(rows0 + quad * 4 + reg) * 256 + wv * 64 + lo16 * 4] = o;
    }

    // V GEMM: K=96, C-init = b1 (folded)
    {
        float b1f[4];
        #pragma unroll
        for (int nt = 0; nt < 4; ++nt) b1f[nt] = b1[wv * 64 + nt * 16 + lo16];
        #pragma unroll
        for (int nt = 0; nt < 4; ++nt)
            #pragma unroll
            for (int reg = 0; reg < 4; ++reg) acc[nt][reg] = b1f[nt];
    }
    #pragma unroll
    for (int ks = 0; ks < 3; ++ks) {
        bf16x8 afr = *(const bf16x8*)&etile[lo16 * 104 + ks * 32 + quad * 8];
        #pragma unroll
        for (int nt = 0; nt < 4; ++nt) {
            int n = wv * 64 + nt * 16 + lo16;
            bf16x8 bfr = *(const bf16x8*)&w1cT[(size_t)n * 96 + ks * 32 + quad * 8];
            acc[nt] = __builtin_amdgcn_mfma_f32_16x16x32_bf16(afr, bfr, acc[nt], 0, 0, 0);
        }
    }
    #pragma unroll
    for (int reg = 0; reg < 4; ++reg) {
        f32x4 o = {acc[0][reg], acc[1][reg], acc[2][reg], acc[3][reg]};
        *(f32x4*)&V_p[(size_t)(rows0 + quad * 4 + reg) * 256 + wv * 64 + lo16 * 4] = o;
    }
}

// ---------------- K_main ---------------------------------------------------
__global__ __launch_bounds__(512, 4) void k_main(
    const float* __restrict__ xyz,
    const unsigned short* __restrict__ w1bT, const unsigned short* __restrict__ w2T,
    const float* __restrict__ U_p, const float* __restrict__ V_p,
    const float* __restrict__ g1, const float* __restrict__ be1,
    const float* __restrict__ b2, const float* __restrict__ g2,
    const float* __restrict__ be2,
    unsigned int* __restrict__ pooled_r)
{
    // rels (128 x 32+8, stride 40) unioned with h1s (128 x 256+8, stride 264)
    __shared__ __align__(16) unsigned short smem[128 * 264];   // 67584 B
    __shared__ unsigned long long bmask[4][64];
    __shared__ int   idxs[128];
    __shared__ float ctr[4][3];
    __shared__ float reds[128][4][2];
    __shared__ float musig[128][2];
    __shared__ unsigned int pool_s[256];
    unsigned short* rels = smem;  // stride 40 (dead once stage-1 MFMAs done)
    unsigned short* h1s  = smem;  // stride 264 (k-permuted within 64-blocks)

    const int N = 4096;
    int tid = threadIdx.x, wv = tid >> 6, lane = tid & 63;
    int lo16 = lane & 15, quad = lane >> 4;
    int wvM = wv >> 2, wvN = wv & 3;           // 2(M) x 4(N) wave grid
    int b = blockIdx.x & 3;                    // batch-major for L2 locality
    int i0 = (blockIdx.x >> 2) * 4;
    int rep = (blockIdx.x >> 2) & 31;          // pooled replica
    size_t base = (size_t)b * N;
    const float* xb = xyz + base * 3;

    // hoisted: rel-part stage-1 weights (independent of LDS)
    bf16x8 bfrR[4];
    #pragma unroll
    for (int nt = 0; nt < 4; ++nt) {
        int n = wvN * 64 + nt * 16 + lo16;
        bfrR[nt] = *(const bf16x8*)&w1bT[(size_t)n * 32 + quad * 8];
    }

    // P0a: centers + pool_s init
    if (tid < 256) pool_s[tid] = fenc(-1e19f);
    if (tid < 12) { int p = tid / 3, a = tid - 3 * p; ctr[p][a] = xb[(i0 + p) * 3 + a]; }
    // exact fp32 threshold: largest float <= (double)0.16*0.16  (validated R9)
    const double r2d = 0.16 * 0.16;
    float T = (float)r2d;
    if ((double)T > r2d) T = __uint_as_float(__float_as_uint(T) - 1u);
    // P0c phase A: each wave scans 8 chunks, all 4 centers per point load
    {
        f32x4 cA = *(const f32x4*)(xb + (size_t)i0 * 3);
        f32x4 cB = *(const f32x4*)(xb + (size_t)i0 * 3 + 4);
        f32x4 cC = *(const f32x4*)(xb + (size_t)i0 * 3 + 8);
        float cx0 = cA.x, cy0 = cA.y, cz0 = cA.z;
        float cx1 = cA.w, cy1 = cB.x, cz1 = cB.y;
        float cx2 = cB.z, cy2 = cB.w, cz2 = cC.x;
        float cx3 = cC.y, cy3 = cC.z, cz3 = cC.w;
        #pragma unroll 2
        for (int i = 0; i < 8; ++i) {
            int chunk = wv * 8 + i;
            int j = chunk * 64 + lane;
            const float* pp = xb + (size_t)j * 3;
            float px = pp[0], py = pp[1], pz = pp[2];
            float dx0 = __fsub_rn(px, cx0), dy0 = __fsub_rn(py, cy0), dz0 = __fsub_rn(pz, cz0);
            float sq0 = __fadd_rn(__fadd_rn(__fmul_rn(dx0, dx0), __fmul_rn(dy0, dy0)),
                                  __fmul_rn(dz0, dz0));
            unsigned long long m0 = __ballot(sq0 <= T);
            float dx1 = __fsub_rn(px, cx1), dy1 = __fsub_rn(py, cy1), dz1 = __fsub_rn(pz, cz1);
            float sq1 = __fadd_rn(__fadd_rn(__fmul_rn(dx1, dx1), __fmul_rn(dy1, dy1)),
                                  __fmul_rn(dz1, dz1));
            unsigned long long m1 = __ballot(sq1 <= T);
            float dx2 = __fsub_rn(px, cx2), dy2 = __fsub_rn(py, cy2), dz2 = __fsub_rn(pz, cz2);
            float sq2 = __fadd_rn(__fadd_rn(__fmul_rn(dx2, dx2), __fmul_rn(dy2, dy2)),
                                  __fmul_rn(dz2, dz2));
            unsigned long long m2 = __ballot(sq2 <= T);
            float dx3 = __fsub_rn(px, cx3), dy3 = __fsub_rn(py, cy3), dz3 = __fsub_rn(pz, cz3);
            float sq3 = __fadd_rn(__fadd_rn(__fmul_rn(dx3, dx3), __fmul_rn(dy3, dy3)),
                                  __fmul_rn(dz3, dz3));
            unsigned long long m3 = __ballot(sq3 <= T);
            if (lane == 0) {
                bmask[0][chunk] = m0; bmask[1][chunk] = m1;
                bmask[2][chunk] = m2; bmask[3][chunk] = m3;
            }
        }
    }
    __syncthreads();
    // P0c phase B: waves 0..3 select first 32 by ascending index (one center each)
    if (wv < 4) {
        int p = wv;
        unsigned long long m = bmask[p][lane];
        int c = __popcll(m);
        int inc = c;
        #pragma unroll
        for (int d = 1; d <= 32; d <<= 1) {
            int v = __shfl_up(inc, d);
            if (lane >= d) inc += v;
        }
        int exc = inc - c;
        int total = __shfl(inc, 63);
        unsigned long long lm = __ballot(m != 0ull);
        int fl = __ffsll(lm) - 1;                       // total>=1 (center in ball)
        unsigned long long mf = (unsigned long long)__shfl((long long)m, fl);
        int firstj = fl * 64 + __ffsll(mf) - 1;
        unsigned long long mm = m;
        int t = 0;
        while (mm != 0ull && (exc + t) < 32) {
            int bpos = __ffsll(mm) - 1;
            idxs[p * 32 + exc + t] = lane * 64 + bpos;
            mm &= mm - 1; ++t;
        }
        if (lane >= total && lane < 32) idxs[p * 32 + lane] = firstj;  // pad
    }
    __syncthreads();

    // P1b: rel xyz (cols 0..2) + rel emb (3..26) + zeros (27..31)
    {
        int r = tid & 127, part = tid >> 7;
        int p = r >> 5;
        int j = idxs[r];
        float rx = xb[j * 3]     - ctr[p][0];
        float ry = xb[j * 3 + 1] - ctr[p][1];
        float rz = xb[j * 3 + 2] - ctr[p][2];
        unsigned short* arow = &rels[r * 40];
        if (part == 0) {
            *(unsigned int*)&arow[0] = pack2(rx, ry);
            arow[2] = f2bf(rz);
            arow[27] = 0;
            *(u32x2*)&arow[28] = (u32x2){0u, 0u};
        } else {
            int a = part - 1;
            float cv = (a == 0) ? rx : ((a == 1) ? ry : rz);
            const float fr4[4] = {1.f, 0.046415888336127774f,
                                  0.0021544346900318843f, 1e-4f};  // 10000^(-j/3)
            float sn[4], cs[4];
            #pragma unroll
            for (int tt = 0; tt < 4; ++tt) {
                float ang = cv * fr4[tt];
                sn[tt] = __sinf(ang); cs[tt] = __cosf(ang);
            }
            arow[3 + a * 8 + 0] = f2bf(sn[0]); arow[3 + a * 8 + 1] = f2bf(sn[1]);
            arow[3 + a * 8 + 2] = f2bf(sn[2]); arow[3 + a * 8 + 3] = f2bf(sn[3]);
            arow[3 + a * 8 + 4] = f2bf(cs[0]); arow[3 + a * 8 + 5] = f2bf(cs[1]);
            arow[3 + a * 8 + 6] = f2bf(cs[2]); arow[3 + a * 8 + 7] = f2bf(cs[3]);
        }
    }
    __syncthreads();

    // P2: C-init = U[j] + V'[c]  (b1 folded into V'); then rel MFMA K=32
    const int arow0 = wvM * 64;
    f32x4 acc[4][4];
    #pragma unroll
    for (int mt = 0; mt < 4; ++mt) {
        int cl = wvM * 2 + (mt >> 1);   // center of rows [arow0+mt*16, +16)
        f32x4 vv = *(const f32x4*)&V_p[(size_t)(base + i0 + cl) * 256 + wvN * 64 + lo16 * 4];
        #pragma unroll
        for (int reg = 0; reg < 4; ++reg) {
            int r = arow0 + mt * 16 + quad * 4 + reg;
            int j = idxs[r];
            f32x4 uu = *(const f32x4*)&U_p[(size_t)(base + j) * 256 + wvN * 64 + lo16 * 4];
            #pragma unroll
            for (int nt = 0; nt < 4; ++nt) acc[mt][nt][reg] = uu[nt] + vv[nt];
        }
    }
    #pragma unroll
    for (int mt = 0; mt < 4; ++mt) {
        bf16x8 afr = *(const bf16x8*)&rels[(arow0 + mt * 16 + lo16) * 40 + quad * 8];
        #pragma unroll
        for (int nt = 0; nt < 4; ++nt)
            acc[mt][nt] = __builtin_amdgcn_mfma_f32_16x16x32_bf16(
                afr, bfrR[nt], acc[mt][nt], 0, 0, 0);
    }

    // P3: LN1 stats (DPP + cross-wave reds) -> gelu -> h1s (pi-packed b64)
    #pragma unroll
    for (int mt = 0; mt < 4; ++mt) {
        #pragma unroll
        for (int reg = 0; reg < 4; ++reg) {
            float s1 = 0.f, s2 = 0.f;
            #pragma unroll
            for (int nt = 0; nt < 4; ++nt) { float v = acc[mt][nt][reg]; s1 += v; s2 = fmaf(v, v, s2); }
            s1 = rowsum16(s1); s2 = rowsum16(s2);
            if (lo16 == 0) {
                int r = arow0 + mt * 16 + quad * 4 + reg;
                reds[r][wvN][0] = s1; reds[r][wvN][1] = s2;
            }
        }
    }
    __syncthreads();   // reds ready; all waves done reading rels
    // R26: per-wave redundant musig — lane L computes row arow0+L. The 4 wvN
    // waves race on identical values (same expression, same inputs -> bit-
    // identical); each wave writes every row it later reads, so same-wave
    // in-order DS semantics make a second barrier unnecessary.
    {
        int r = arow0 + lane;
        float s1 = reds[r][0][0] + reds[r][1][0] + reds[r][2][0] + reds[r][3][0];
        float s2 = reds[r][0][1] + reds[r][1][1] + reds[r][2][1] + reds[r][3][1];
        float mu = s1 * (1.f / 256.f);
        float var = fmaxf(s2 * (1.f / 256.f) - mu * mu, 0.f);
        musig[r][0] = mu; musig[r][1] = rsqrtf(var + LN_EPS);
    }
    {
        float g1f[4], be1f[4];
        #pragma unroll
        for (int nt = 0; nt < 4; ++nt) {
            int n = wvN * 64 + nt * 16 + lo16;
            g1f[nt] = g1[n]; be1f[nt] = be1[n];
        }
        #pragma unroll
        for (int mt = 0; mt < 4; ++mt) {
            #pragma unroll
            for (int reg = 0; reg < 4; ++reg) {
                int r = arow0 + mt * 16 + quad * 4 + reg;
                float mu = musig[r][0], rs = musig[r][1];
                float v0 = gelu_fast(fmaf((acc[mt][0][reg] - mu) * rs, g1f[0], be1f[0]));
                float v1 = gelu_fast(fmaf((acc[mt][1][reg] - mu) * rs, g1f[1], be1f[1]));
                float v2 = gelu_fast(fmaf((acc[mt][2][reg] - mu) * rs, g1f[2], be1f[2]));
                float v3 = gelu_fast(fmaf((acc[mt][3][reg] - mu) * rs, g1f[3], be1f[3]));
                u32x2 w; w.x = pack2(v0, v1); w.y = pack2(v2, v3);
                *(u32x2*)&h1s[r * 264 + wvN * 64 + lo16 * 4] = w;   // pi(n)=lo16*4+nt
            }
        }
    }
    __syncthreads();   // h1s ready

    // P4: stage-2 MFMA K=256 (pi-permuted; w2T matches); C-init = b2
    {
        float b2f[4];
        #pragma unroll
        for (int nt = 0; nt < 4; ++nt) b2f[nt] = b2[wvN * 64 + nt * 16 + lo16];
        #pragma unroll
        for (int mt = 0; mt < 4; ++mt)
            #pragma unroll
            for (int nt = 0; nt < 4; ++nt)
                #pragma unroll
                for (int reg = 0; reg < 4; ++reg) acc[mt][nt][reg] = b2f[nt];
    }
    for (int ks = 0; ks < 8; ++ks) {
        bf16x8 bfr[4], afr[4];
        #pragma unroll
        for (int nt = 0; nt < 4; ++nt) {
            int n = wvN * 64 + nt * 16 + lo16;
            bfr[nt] = *(const bf16x8*)&w2T[(size_t)n * 256 + ks * 32 + quad * 8];
        }
        #pragma unroll
        for (int mt = 0; mt < 4; ++mt)
            afr[mt] = *(const bf16x8*)&h1s[(arow0 + mt * 16 + lo16) * 264 + ks * 32 + quad * 8];
        #pragma unroll
        for (int mt = 0; mt < 4; ++mt)
            #pragma unroll
            for (int nt = 0; nt < 4; ++nt)
                acc[mt][nt] = __builtin_amdgcn_mfma_f32_16x16x32_bf16(
                    afr[mt], bfr[nt], acc[mt][nt], 0, 0, 0);
    }

    // P5: LN2 stats (DPP + reds), per-wave musig (R26), normalize,
    // col-max -> LDS pool_s -> global
    {
        #pragma unroll
        for (int mt = 0; mt < 4; ++mt) {
            #pragma unroll
            for (int reg = 0; reg < 4; ++reg) {
                float s1 = 0.f, s2 = 0.f;
                #pragma unroll
                for (int nt = 0; nt < 4; ++nt) { float v = acc[mt][nt][reg]; s1 += v; s2 = fmaf(v, v, s2); }
                s1 = rowsum16(s1); s2 = rowsum16(s2);
                if (lo16 == 0) {
                    int r = arow0 + mt * 16 + quad * 4 + reg;
                    reds[r][wvN][0] = s1; reds[r][wvN][1] = s2;
                }
            }
        }
        __syncthreads();
        {
            int r = arow0 + lane;
            float s1 = reds[r][0][0] + reds[r][1][0] + reds[r][2][0] + reds[r][3][0];
            float s2 = reds[r][0][1] + reds[r][1][1] + reds[r][2][1] + reds[r][3][1];
            float mu = s1 * (1.f / 256.f);
            float var = fmaxf(s2 * (1.f / 256.f) - mu * mu, 0.f);
            musig[r][0] = mu; musig[r][1] = rsqrtf(var + LN_EPS);
        }

        float g2f[4], be2f[4];
        #pragma unroll
        for (int nt = 0; nt < 4; ++nt) {
            int n = wvN * 64 + nt * 16 + lo16;
            g2f[nt] = g2[n]; be2f[nt] = be2[n];
        }
        float mx[4] = {-1e30f, -1e30f, -1e30f, -1e30f};
        #pragma unroll
        for (int mt = 0; mt < 4; ++mt) {
            #pragma unroll
            for (int reg = 0; reg < 4; ++reg) {
                int r = arow0 + mt * 16 + quad * 4 + reg;
                float mu = musig[r][0], rs = musig[r][1];
                #pragma unroll
                for (int nt = 0; nt < 4; ++nt) {
                    float v = fmaf((acc[mt][nt][reg] - mu) * rs, g2f[nt], be2f[nt]);
                    mx[nt] = fmaxf(mx[nt], v);
                }
            }
        }
        #pragma unroll
        for (int nt = 0; nt < 4; ++nt) {
            mx[nt] = fmaxf(mx[nt], __shfl_xor(mx[nt], 16));
            mx[nt] = fmaxf(mx[nt], __shfl_xor(mx[nt], 32));
        }
        if (quad == 0) {
            #pragma unroll
            for (int nt = 0; nt < 4; ++nt)
                atomicMax(&pool_s[wvN * 64 + nt * 16 + lo16], fenc(mx[nt]));
        }
    }
    // flush pool_s to this block's replica (256 coalesced atomics)
    __syncthreads();
    if (tid < 256)
        atomicMax(pooled_r + rep * 1024 + b * 256 + tid, pool_s[tid]);
}

// ---------------- K_final: replica max-reduce + final MLPs ------------------
// 4 blocks (one per batch) x 256 threads; thread owns output col c = tid.
__global__ __launch_bounds__(256) void k_final(
    const unsigned int* __restrict__ pooled_r,
    const float* __restrict__ pw1, const float* __restrict__ pb1,
    const float* __restrict__ pg1, const float* __restrict__ pbe1,
    const float* __restrict__ pw2, const float* __restrict__ pb2,
    const float* __restrict__ pg2, const float* __restrict__ pbe2,
    float* __restrict__ out)
{
    __shared__ float xw[256], xh[256];
    __shared__ float lred[2][4];
    int tid = threadIdx.x, wv = tid >> 6;
    int bb = blockIdx.x;

    // replica max-reduce for this thread's column
    {
        unsigned int mv = pooled_r[bb * 256 + tid];
        #pragma unroll
        for (int r = 1; r < 32; ++r) {
            unsigned int v = pooled_r[r * 1024 + bb * 256 + tid];
            mv = (v > mv) ? v : mv;
        }
        xw[tid] = fdec(mv);
    }
    __syncthreads();

    // MLP1: a1[c] = pb1[c] + sum_k xw[k]*pw1[k][c]
    float a1 = pb1[tid];
    #pragma unroll 8
    for (int k = 0; k < 256; ++k)
        a1 = fmaf(xw[k], pw1[(size_t)k * 256 + tid], a1);
    // LN over cols (4-wave reduce)
    float s1 = a1, s2 = a1 * a1;
    s1 = rowsum16(s1); s2 = rowsum16(s2);
    s1 += __shfl_xor(s1, 16); s2 += __shfl_xor(s2, 16);
    s1 += __shfl_xor(s1, 32); s2 += __shfl_xor(s2, 32);
    if ((tid & 63) == 0) { lred[0][wv] = s1; lred[1][wv] = s2; }
    __syncthreads();
    s1 = lred[0][0] + lred[0][1] + lred[0][2] + lred[0][3];
    s2 = lred[1][0] + lred[1][1] + lred[1][2] + lred[1][3];
    float mu = s1 * (1.f / 256.f);
    float rs = rsqrtf(fmaxf(s2 * (1.f / 256.f) - mu * mu, 0.f) + LN_EPS);
    xh[tid] = gelu_fast(fmaf((a1 - mu) * rs, pg1[tid], pbe1[tid]));
    __syncthreads();

    // MLP2
    float a2 = pb2[tid];
    #pragma unroll 8
    for (int k = 0; k < 256; ++k)
        a2 = fmaf(xh[k], pw2[(size_t)k * 256 + tid], a2);
    s1 = a2; s2 = a2 * a2;
    s1 = rowsum16(s1); s2 = rowsum16(s2);
    s1 += __shfl_xor(s1, 16); s2 += __shfl_xor(s2, 16);
    s1 += __shfl_xor(s1, 32); s2 += __shfl_xor(s2, 32);
    if ((tid & 63) == 0) { lred[0][wv] = s1; lred[1][wv] = s2; }
    __syncthreads();
    s1 = lred[0][0] + lred[0][1] + lred[0][2] + lred[0][3];
    s2 = lred[1][0] + lred[1][1] + lred[1][2] + lred[1][3];
    mu = s1 * (1.f / 256.f);
    rs = rsqrtf(fmaxf(s2 * (1.f / 256.f) - mu * mu, 0.f) + LN_EPS);
    out[bb * 256 + tid] = fmaf((a2 - mu) * rs, pg2[tid], pbe2[tid]);
}

// ---------------- launch ---------------------------------------------------
extern "C" void kernel_launch(void* const* d_in, const int* in_sizes, int n_in,
                              void* d_out, int out_size, void* d_ws, size_t ws_size,
                              hipStream_t stream)
{
    char* ws = (char*)d_ws;
    unsigned short* w2T      = (unsigned short*)ws;                      // 128 KB
    unsigned short* w1aT     = (unsigned short*)(ws + (128u << 10));     // 32 KB
    unsigned short* w1cT     = (unsigned short*)(ws + (160u << 10));     // 48 KB
    unsigned short* w1bT     = (unsigned short*)(ws + (208u << 10));     // 16 KB
    unsigned int*   pooled_r = (unsigned int*)(ws + (224u << 10));       // 128 KB
    float*          U_p      = (float*)(ws + (512u << 10));              // 16 MB
    float*          V_p      = (float*)(ws + (512u << 10) + (16u << 20)); // 16 MB

    const float* xyz = (const float*)d_in[0];
    const float* pf  = (const float*)d_in[1];
    const float* w1  = (const float*)d_in[2];
    const float* b1  = (const float*)d_in[3];

    k_prep<<<30, 256, 0, stream>>>(w1, (const float*)d_in[6],
                                   w2T, w1aT, w1cT, w1bT, pooled_r);
    k_pre<<<1024, 256, 0, stream>>>(xyz, pf, w1aT, w1cT, b1, U_p, V_p);
    k_main<<<4096, 512, 0, stream>>>(xyz, w1bT, w2T, U_p, V_p,
                                     (const float*)d_in[4], (const float*)d_in[5],
                                     (const float*)d_in[7], (const float*)d_in[8],
                                     (const float*)d_in[9], pooled_r);
    k_final<<<4, 256, 0, stream>>>(pooled_r,
                                   (const float*)d_in[10], (const float*)d_in[11],
                                   (const float*)d_in[12], (const float*)d_in[13],
                                   (const float*)d_in[14], (const float*)d_in[15],
                                   (const float*)d_in[16], (const float*)d_in[17],
                                   (float*)d_out);
}